// Round 5
// baseline (532.289 us; speedup 1.0000x reference)
//
#include <hip/hip_runtime.h>
#include <hip/hip_bf16.h>

#define NEG_SLOPE 0.2f
#define BN_EPS 1e-5f

// bucketed CSR build: 64 nodes per bucket; src packs into 32-(BKT_SHIFT) bits (needs N < 2^26)
#define BKT_SHIFT 6
#define BKT_NPB 64

__device__ __forceinline__ float wred_sum(float v) {
    #pragma unroll
    for (int m = 32; m > 0; m >>= 1) v += __shfl_xor(v, m);
    return v;
}
__device__ __forceinline__ float wred_max(float v) {
    #pragma unroll
    for (int m = 32; m > 0; m >>= 1) v = fmaxf(v, __shfl_xor(v, m));
    return v;
}

__device__ __forceinline__ unsigned pack_bf16(float a, float b) {
    __hip_bfloat162 t;
    t.x = __float2bfloat16(a);
    t.y = __float2bfloat16(b);
    return *(unsigned*)&t;
}
__device__ __forceinline__ float2 unpack_bf16(unsigned u) {
    __hip_bfloat162 t = *(__hip_bfloat162*)&u;
    return {__bfloat162float(t.x), __bfloat162float(t.y)};
}

// ---------------- CSR build ----------------
__global__ void hist_kernel(const int* __restrict__ ei, int E, int Et, int* __restrict__ deg) {
    int idx = blockIdx.x * blockDim.x + threadIdx.x;
    if (idx >= Et) return;
    int d = (idx < E) ? ei[E + idx] : (idx - E);
    atomicAdd(&deg[d], 1);
}

#define SCAN_CHUNK 2048

__global__ __launch_bounds__(256) void scan_blocksum(const int* __restrict__ deg,
                                                     int* __restrict__ bsum, int n) {
    __shared__ int red[256];
    int b = blockIdx.x, t = threadIdx.x;
    int base = b * SCAN_CHUNK + t * 8;
    int s = 0;
    #pragma unroll
    for (int i = 0; i < 8; ++i) { int idx = base + i; if (idx < n) s += deg[idx]; }
    red[t] = s;
    __syncthreads();
    for (int off = 128; off > 0; off >>= 1) {
        if (t < off) red[t] += red[t + off];
        __syncthreads();
    }
    if (t == 0) bsum[b] = red[0];
}

__global__ __launch_bounds__(1024) void scan_bsums(const int* __restrict__ bsum,
                                                   int* __restrict__ bpre, int nb) {
    __shared__ int s[1024];
    int t = threadIdx.x;
    int v = (t < nb) ? bsum[t] : 0;
    s[t] = v;
    __syncthreads();
    for (int off = 1; off < 1024; off <<= 1) {
        int u = (t >= off) ? s[t - off] : 0;
        __syncthreads();
        s[t] += u;
        __syncthreads();
    }
    if (t < nb) bpre[t] = s[t] - v;
    if (t == 1023) bpre[nb] = s[1023];
}

__global__ __launch_bounds__(256) void scan_scatter(const int* __restrict__ deg,
                                                    const int* __restrict__ bpre,
                                                    int* __restrict__ offs,
                                                    int n, int nb) {
    __shared__ int red[256];
    int b = blockIdx.x, t = threadIdx.x;
    int base = b * SCAN_CHUNK + t * 8;
    int loc[8];
    int s = 0;
    #pragma unroll
    for (int i = 0; i < 8; ++i) {
        int idx = base + i;
        int d = (idx < n) ? deg[idx] : 0;
        loc[i] = s;
        s += d;
    }
    red[t] = s;
    __syncthreads();
    int v = s;
    for (int off = 1; off < 256; off <<= 1) {
        int u = (t >= off) ? red[t - off] : 0;
        __syncthreads();
        red[t] += u;
        __syncthreads();
    }
    int tpre = red[t] - v + bpre[b];
    #pragma unroll
    for (int i = 0; i < 8; ++i) {
        int idx = base + i;
        if (idx < n) offs[idx] = tpre + loc[i];
    }
    if (b == 0 && t == 0) offs[n] = bpre[nb];
}

// init per-bucket append cursor = offs[first node of bucket]
__global__ void bucket_init(const int* __restrict__ offs, int* __restrict__ bcur, int nbuckets) {
    int b = blockIdx.x * blockDim.x + threadIdx.x;
    if (b < nbuckets) bcur[b] = offs[b << BKT_SHIFT];
}

// phase B: append packed (src, dst&63) into the bucket's csr segment (write-local)
__global__ void bucket_scatter(const int* __restrict__ ei, int E, int Et,
                               int* __restrict__ bcur, unsigned* __restrict__ staged) {
    int idx = blockIdx.x * blockDim.x + threadIdx.x;
    if (idx >= Et) return;
    int s, d;
    if (idx < E) { s = ei[idx]; d = ei[E + idx]; }
    else         { s = idx - E; d = idx - E; }
    int bkt = d >> BKT_SHIFT;
    int pos = atomicAdd(&bcur[bkt], 1);
    staged[pos] = ((unsigned)s << BKT_SHIFT) | (unsigned)(d & (BKT_NPB - 1));
}

// phase C: one block per bucket; LDS counters resolve final csr position
__global__ __launch_bounds__(256) void bucket_place(const unsigned* __restrict__ staged,
                                                    const int* __restrict__ offs,
                                                    int* __restrict__ csr, int Nn, int nbuckets) {
    __shared__ int lcur[BKT_NPB];
    int b = blockIdx.x;
    int t = threadIdx.x;
    int node0 = b << BKT_SHIFT;
    int nend  = min(node0 + BKT_NPB, Nn);
    if (t < nend - node0) lcur[t] = offs[node0 + t];
    __syncthreads();
    int ebeg = offs[node0];
    int eend = offs[nend];
    for (int p = ebeg + t; p < eend; p += 256) {
        unsigned v = staged[p];
        int s  = (int)(v >> BKT_SHIFT);
        int dl = (int)(v & (BKT_NPB - 1));
        int pos = atomicAdd(&lcur[dl], 1);
        csr[pos] = s;
    }
}

// ---------------- Layer 1 GEMM + fused al1, bf16-packed output ----------------
__global__ __launch_bounds__(256) void gemm1_tiled(const float* __restrict__ x,
                                                   const float* __restrict__ W,
                                                   const float* __restrict__ a1s,
                                                   const float* __restrict__ a1d,
                                                   unsigned* __restrict__ h1b,
                                                   float* __restrict__ als,
                                                   float* __restrict__ ald, int Nn) {
    __shared__ float As[64][33];
    __shared__ float Bs[32][132];
    __shared__ float4 red4[64][17];
    int t  = threadIdx.x;
    int tx = t & 15;
    int ty = t >> 4;
    int br = blockIdx.x * 64;

    float acc[4][8];
    #pragma unroll
    for (int i = 0; i < 4; ++i)
        #pragma unroll
        for (int j = 0; j < 8; ++j) acc[i][j] = 0.f;

    int k4  = t & 7;
    int rowA = t >> 3;

    for (int k0 = 0; k0 < 128; k0 += 32) {
        #pragma unroll
        for (int i = 0; i < 2; ++i) {
            int r  = rowA + 32 * i;
            int gr = min(br + r, Nn - 1);
            float4 v = *(const float4*)(x + (size_t)gr * 128 + k0 + 4 * k4);
            As[r][4 * k4 + 0] = v.x; As[r][4 * k4 + 1] = v.y;
            As[r][4 * k4 + 2] = v.z; As[r][4 * k4 + 3] = v.w;
        }
        #pragma unroll
        for (int i = 0; i < 4; ++i) {
            int f  = t + 256 * i;
            int kk = f >> 5, c4 = f & 31;
            *(float4*)&Bs[kk][4 * c4] = *(const float4*)(W + (size_t)(k0 + kk) * 128 + 4 * c4);
        }
        __syncthreads();
        #pragma unroll
        for (int kk = 0; kk < 32; ++kk) {
            float4 b0 = *(const float4*)&Bs[kk][4 * tx];
            float4 b1 = *(const float4*)&Bs[kk][64 + 4 * tx];
            #pragma unroll
            for (int i = 0; i < 4; ++i) {
                float a = As[4 * ty + i][kk];
                acc[i][0] += a * b0.x; acc[i][1] += a * b0.y;
                acc[i][2] += a * b0.z; acc[i][3] += a * b0.w;
                acc[i][4] += a * b1.x; acc[i][5] += a * b1.y;
                acc[i][6] += a * b1.z; acc[i][7] += a * b1.w;
            }
        }
        __syncthreads();
    }
    float s_lo[4], s_hi[4], d_lo[4], d_hi[4];
    #pragma unroll
    for (int j = 0; j < 4; ++j) {
        s_lo[j] = a1s[4 * tx + j];      s_hi[j] = a1s[64 + 4 * tx + j];
        d_lo[j] = a1d[4 * tx + j];      d_hi[j] = a1d[64 + 4 * tx + j];
    }
    #pragma unroll
    for (int i = 0; i < 4; ++i) {
        float4 pp = {0.f, 0.f, 0.f, 0.f};
        #pragma unroll
        for (int j = 0; j < 4; ++j) {
            pp.x += acc[i][j] * s_lo[j];
            pp.y += acc[i][4 + j] * s_hi[j];
            pp.z += acc[i][j] * d_lo[j];
            pp.w += acc[i][4 + j] * d_hi[j];
        }
        red4[4 * ty + i][tx] = pp;
        int r = br + 4 * ty + i;
        if (r < Nn) {
            uint2 lo = {pack_bf16(acc[i][0], acc[i][1]), pack_bf16(acc[i][2], acc[i][3])};
            uint2 hi = {pack_bf16(acc[i][4], acc[i][5]), pack_bf16(acc[i][6], acc[i][7])};
            *(uint2*)(h1b + (size_t)r * 64 + 2 * tx)      = lo;
            *(uint2*)(h1b + (size_t)r * 64 + 32 + 2 * tx) = hi;
        }
    }
    __syncthreads();
    if (t < 64) {
        int r = br + t;
        if (r < Nn) {
            float4 s = {0.f, 0.f, 0.f, 0.f};
            #pragma unroll
            for (int xx = 0; xx < 16; ++xx) {
                float4 p = red4[t][xx];
                s.x += p.x; s.y += p.y; s.z += p.z; s.w += p.w;
            }
            als[r * 2] = s.x; als[r * 2 + 1] = s.y;
            ald[r * 2] = s.z; ald[r * 2 + 1] = s.w;
        }
    }
}

// ---------------- per-node edge softmax, 2-pass: store unnormalized exp + 1/s ----------------
template <int H>
__global__ void edge_softmax_kernel(const int* __restrict__ offs, const int* __restrict__ csr,
                                    const float* __restrict__ als, const float* __restrict__ ald,
                                    float* __restrict__ lg, float* __restrict__ invs, int Nn) {
    int wid = threadIdx.x >> 6, lane = threadIdx.x & 63;
    int n = blockIdx.x * 4 + wid;
    if (n >= Nn) return;
    int b = offs[n], e = offs[n + 1];
    float aldn[H];
    #pragma unroll
    for (int h = 0; h < H; ++h) aldn[h] = ald[n * H + h];
    float mx[H];
    #pragma unroll
    for (int h = 0; h < H; ++h) mx[h] = -1e30f;
    for (int p = b + lane; p < e; p += 64) {
        int s = csr[p];
        #pragma unroll
        for (int h = 0; h < H; ++h) {
            float l = als[s * H + h] + aldn[h];
            l = (l > 0.f) ? l : NEG_SLOPE * l;
            lg[p * H + h] = l;
            mx[h] = fmaxf(mx[h], l);
        }
    }
    #pragma unroll
    for (int h = 0; h < H; ++h) mx[h] = wred_max(mx[h]);
    float sm[H];
    #pragma unroll
    for (int h = 0; h < H; ++h) sm[h] = 0.f;
    for (int p = b + lane; p < e; p += 64) {
        #pragma unroll
        for (int h = 0; h < H; ++h) {
            float t = expf(lg[p * H + h] - mx[h]);
            lg[p * H + h] = t;
            sm[h] += t;
        }
    }
    #pragma unroll
    for (int h = 0; h < H; ++h) sm[h] = wred_sum(sm[h]);
    if (lane == 0) {
        #pragma unroll
        for (int h = 0; h < H; ++h) invs[n * H + h] = 1.f / (sm[h] + 1e-16f);
    }
}

// ---------------- layer-1 aggregation: bf16 gather, 4 edges in flight ----------------
__global__ __launch_bounds__(256) void agg1_kernel(const int* __restrict__ offs, const int* __restrict__ csr,
                            const unsigned* __restrict__ h1b, const float* __restrict__ ex,
                            const float* __restrict__ invs,
                            const float* __restrict__ b1, const float* __restrict__ gam,
                            const float* __restrict__ bet, const float* __restrict__ mean,
                            const float* __restrict__ var, float* __restrict__ hbn, int Nn) {
    int wid = threadIdx.x >> 6, lane = threadIdx.x & 63;
    int n = blockIdx.x * 4 + wid;
    if (n >= Nn) return;
    int sub = lane >> 4;
    int l16 = lane & 15;
    int head = l16 >> 3;
    int b = offs[n], e = offs[n + 1];
    float acc[8];
    #pragma unroll
    for (int j = 0; j < 8; ++j) acc[j] = 0.f;
    for (int p = b + sub; p < e; p += 4) {
        int s = csr[p];
        float a = ex[p * 2 + head];
        uint4 v = *(const uint4*)(h1b + (size_t)s * 64 + 4 * l16);
        float2 f0 = unpack_bf16(v.x), f1 = unpack_bf16(v.y);
        float2 f2 = unpack_bf16(v.z), f3 = unpack_bf16(v.w);
        acc[0] += f0.x * a; acc[1] += f0.y * a;
        acc[2] += f1.x * a; acc[3] += f1.y * a;
        acc[4] += f2.x * a; acc[5] += f2.y * a;
        acc[6] += f3.x * a; acc[7] += f3.y * a;
    }
    #pragma unroll
    for (int j = 0; j < 8; ++j) {
        acc[j] += __shfl_xor(acc[j], 16);
        acc[j] += __shfl_xor(acc[j], 32);
    }
    if (sub == 0) {
        float inv = invs[n * 2 + head];
        int c = 8 * l16;
        #pragma unroll
        for (int half = 0; half < 2; ++half) {
            int cc = c + 4 * half;
            float4 bb = *(const float4*)(b1 + cc);
            float4 gg = *(const float4*)(gam + cc);
            float4 be = *(const float4*)(bet + cc);
            float4 mm = *(const float4*)(mean + cc);
            float4 vv = *(const float4*)(var + cc);
            float4 o;
            o.x = fmaxf((acc[4*half+0] * inv + bb.x - mm.x) * rsqrtf(vv.x + BN_EPS) * gg.x + be.x, 0.f);
            o.y = fmaxf((acc[4*half+1] * inv + bb.y - mm.y) * rsqrtf(vv.y + BN_EPS) * gg.y + be.y, 0.f);
            o.z = fmaxf((acc[4*half+2] * inv + bb.z - mm.z) * rsqrtf(vv.z + BN_EPS) * gg.z + be.z, 0.f);
            o.w = fmaxf((acc[4*half+3] * inv + bb.w - mm.w) * rsqrtf(vv.w + BN_EPS) * gg.w + be.w, 0.f);
            *(float4*)(hbn + (size_t)n * 128 + cc) = o;
        }
    }
}

// ---------------- layer 2 GEMM tiled + fused al2, bf16-packed output ----------------
__global__ __launch_bounds__(256) void gemm2_tiled(const float* __restrict__ hbn,
                                                   const float* __restrict__ W2,
                                                   const float* __restrict__ a2s,
                                                   const float* __restrict__ a2d,
                                                   unsigned* __restrict__ h2b,
                                                   float* __restrict__ als, float* __restrict__ ald,
                                                   int Nn) {
    __shared__ float As[64][33];
    __shared__ float Bs[128][68];
    __shared__ float redS[64][17];
    __shared__ float redD[64][17];
    int t  = threadIdx.x;
    int tx = t & 15;
    int ty = t >> 4;
    int br = blockIdx.x * 64;

    #pragma unroll
    for (int i = 0; i < 8; ++i) {
        int f  = t + 256 * i;
        int kk = f >> 4, c4 = f & 15;
        float4 v = {0.f, 0.f, 0.f, 0.f};
        if (c4 < 10) v = *(const float4*)(W2 + (size_t)kk * 40 + 4 * c4);
        *(float4*)&Bs[kk][4 * c4] = v;
    }
    float as4[4], ad4[4];
    #pragma unroll
    for (int j = 0; j < 4; ++j) {
        int c = 4 * tx + j;
        as4[j] = (c < 40) ? a2s[c] : 0.f;
        ad4[j] = (c < 40) ? a2d[c] : 0.f;
    }

    float acc[4][4];
    #pragma unroll
    for (int i = 0; i < 4; ++i)
        #pragma unroll
        for (int j = 0; j < 4; ++j) acc[i][j] = 0.f;

    int k4  = t & 7;
    int rowA = t >> 3;
    __syncthreads();

    for (int k0 = 0; k0 < 128; k0 += 32) {
        #pragma unroll
        for (int i = 0; i < 2; ++i) {
            int r  = rowA + 32 * i;
            int gr = min(br + r, Nn - 1);
            float4 v = *(const float4*)(hbn + (size_t)gr * 128 + k0 + 4 * k4);
            As[r][4 * k4 + 0] = v.x; As[r][4 * k4 + 1] = v.y;
            As[r][4 * k4 + 2] = v.z; As[r][4 * k4 + 3] = v.w;
        }
        __syncthreads();
        #pragma unroll
        for (int kk = 0; kk < 32; ++kk) {
            float4 b0 = *(const float4*)&Bs[k0 + kk][4 * tx];
            #pragma unroll
            for (int i = 0; i < 4; ++i) {
                float a = As[4 * ty + i][kk];
                acc[i][0] += a * b0.x; acc[i][1] += a * b0.y;
                acc[i][2] += a * b0.z; acc[i][3] += a * b0.w;
            }
        }
        __syncthreads();
    }
    #pragma unroll
    for (int i = 0; i < 4; ++i) {
        redS[4 * ty + i][tx] = acc[i][0] * as4[0] + acc[i][1] * as4[1] + acc[i][2] * as4[2] + acc[i][3] * as4[3];
        redD[4 * ty + i][tx] = acc[i][0] * ad4[0] + acc[i][1] * ad4[1] + acc[i][2] * ad4[2] + acc[i][3] * ad4[3];
        int r = br + 4 * ty + i;
        if (r < Nn) {
            uint2 pk = {pack_bf16(acc[i][0], acc[i][1]), pack_bf16(acc[i][2], acc[i][3])};
            *(uint2*)(h2b + (size_t)r * 32 + 2 * tx) = pk;
        }
    }
    __syncthreads();
    if (t < 64) {
        int r = br + t;
        if (r < Nn) {
            float sS = 0.f, sD = 0.f;
            #pragma unroll
            for (int xx = 0; xx < 16; ++xx) { sS += redS[t][xx]; sD += redD[t][xx]; }
            als[r] = sS; ald[r] = sD;
        }
    }
}

// ---------------- layer-2 aggregation: bf16 gather, 4 edges in flight, + log_softmax ----------------
__global__ __launch_bounds__(256) void agg2_kernel(const int* __restrict__ offs, const int* __restrict__ csr,
                            const unsigned* __restrict__ h2b, const float* __restrict__ ex,
                            const float* __restrict__ invs, const float* __restrict__ b2,
                            float* __restrict__ out, int Nn) {
    int wid = threadIdx.x >> 6, lane = threadIdx.x & 63;
    int n = blockIdx.x * 4 + wid;
    if (n >= Nn) return;
    int sub = lane >> 4;
    int l16 = lane & 15;
    int b = offs[n], e = offs[n + 1];
    float acc[4];
    #pragma unroll
    for (int j = 0; j < 4; ++j) acc[j] = 0.f;
    for (int p = b + sub; p < e; p += 4) {
        int s = csr[p];
        float a = ex[p];
        uint2 v = *(const uint2*)(h2b + (size_t)s * 32 + 2 * l16);
        float2 f0 = unpack_bf16(v.x), f1 = unpack_bf16(v.y);
        acc[0] += f0.x * a; acc[1] += f0.y * a;
        acc[2] += f1.x * a; acc[3] += f1.y * a;
    }
    #pragma unroll
    for (int j = 0; j < 4; ++j) {
        acc[j] += __shfl_xor(acc[j], 16);
        acc[j] += __shfl_xor(acc[j], 32);
    }
    float inv = invs[n];
    bool valid = (l16 < 10);
    float v0 = -1e30f, v1 = -1e30f, v2 = -1e30f, v3 = -1e30f;
    if (valid) {
        int c = 4 * l16;
        v0 = acc[0] * inv + b2[c];
        v1 = acc[1] * inv + b2[c + 1];
        v2 = acc[2] * inv + b2[c + 2];
        v3 = acc[3] * inv + b2[c + 3];
    }
    float m = wred_max(fmaxf(fmaxf(v0, v1), fmaxf(v2, v3)));
    float es = (valid && sub == 0)
             ? (expf(v0 - m) + expf(v1 - m) + expf(v2 - m) + expf(v3 - m)) : 0.f;
    float ssum = wred_sum(es);
    float lse = m + logf(ssum);
    if (sub == 0 && valid) {
        float4 o = {v0 - lse, v1 - lse, v2 - lse, v3 - lse};
        *(float4*)(out + (size_t)n * 40 + 4 * l16) = o;
    }
}

extern "C" void kernel_launch(void* const* d_in, const int* in_sizes, int n_in,
                              void* d_out, int out_size, void* d_ws, size_t ws_size,
                              hipStream_t stream) {
    const float* x    = (const float*)d_in[0];
    const int*   ei   = (const int*)d_in[1];
    const float* W1   = (const float*)d_in[2];
    const float* a1s  = (const float*)d_in[3];
    const float* a1d  = (const float*)d_in[4];
    const float* b1   = (const float*)d_in[5];
    const float* g1   = (const float*)d_in[6];
    const float* be1  = (const float*)d_in[7];
    const float* mn1  = (const float*)d_in[8];
    const float* vr1  = (const float*)d_in[9];
    const float* W2   = (const float*)d_in[10];
    const float* a2s  = (const float*)d_in[11];
    const float* a2d  = (const float*)d_in[12];
    const float* b2   = (const float*)d_in[13];
    float* out = (float*)d_out;

    const int N  = in_sizes[0] / 128;
    const int E  = in_sizes[1] / 2;
    const int Et = E + N;
    const int nScanB = (N + SCAN_CHUNK - 1) / SCAN_CHUNK;
    const int nBkt   = (N + BKT_NPB - 1) >> BKT_SHIFT;

    char* p = (char*)d_ws;
    auto alloc = [&](size_t bytes) -> void* {
        void* r = (void*)p;
        p += (bytes + 255) & ~(size_t)255;
        return r;
    };
    int*      deg    = (int*)alloc((size_t)N * 4);
    int*      offs   = (int*)alloc((size_t)(N + 1) * 4);
    int*      bsum   = (int*)alloc((size_t)(nScanB + 1) * 4);
    int*      bpre   = (int*)alloc((size_t)(nScanB + 1) * 4);
    int*      bcur   = (int*)alloc((size_t)nBkt * 4);
    unsigned* staged = (unsigned*)alloc((size_t)Et * 4);
    int*      csr    = (int*)alloc((size_t)Et * 4);
    unsigned* h1b    = (unsigned*)alloc((size_t)N * 64 * 4);
    float*    al1sv  = (float*)alloc((size_t)N * 2 * 4);
    float*    al1dv  = (float*)alloc((size_t)N * 2 * 4);
    float*    ex1    = (float*)alloc((size_t)Et * 2 * 4);
    float*    inv1   = (float*)alloc((size_t)N * 2 * 4);
    float*    hbn    = (float*)alloc((size_t)N * 128 * 4);
    unsigned* h2b    = (unsigned*)alloc((size_t)N * 32 * 4);
    float*    al2sv  = (float*)alloc((size_t)N * 4);
    float*    al2dv  = (float*)alloc((size_t)N * 4);
    float*    ex2    = (float*)alloc((size_t)Et * 4);
    float*    inv2   = (float*)alloc((size_t)N * 4);
    (void)ws_size;

    hipMemsetAsync(deg, 0, (size_t)N * 4, stream);

    int tpb = 256;
    hist_kernel<<<(Et + tpb - 1) / tpb, tpb, 0, stream>>>(ei, E, Et, deg);
    scan_blocksum<<<nScanB, 256, 0, stream>>>(deg, bsum, N);
    scan_bsums<<<1, 1024, 0, stream>>>(bsum, bpre, nScanB);
    scan_scatter<<<nScanB, 256, 0, stream>>>(deg, bpre, offs, N, nScanB);
    bucket_init<<<(nBkt + tpb - 1) / tpb, tpb, 0, stream>>>(offs, bcur, nBkt);
    bucket_scatter<<<(Et + tpb - 1) / tpb, tpb, 0, stream>>>(ei, E, Et, bcur, staged);
    bucket_place<<<nBkt, 256, 0, stream>>>(staged, offs, csr, N, nBkt);

    gemm1_tiled<<<(N + 63) / 64, 256, 0, stream>>>(x, W1, a1s, a1d, h1b, al1sv, al1dv, N);
    edge_softmax_kernel<2><<<(N + 3) / 4, 256, 0, stream>>>(offs, csr, al1sv, al1dv, ex1, inv1, N);
    agg1_kernel<<<(N + 3) / 4, 256, 0, stream>>>(offs, csr, h1b, ex1, inv1, b1, g1, be1, mn1, vr1, hbn, N);

    gemm2_tiled<<<(N + 63) / 64, 256, 0, stream>>>(hbn, W2, a2s, a2d, h2b, al2sv, al2dv, N);
    edge_softmax_kernel<1><<<(N + 3) / 4, 256, 0, stream>>>(offs, csr, al2sv, al2dv, ex2, inv2, N);
    agg2_kernel<<<(N + 3) / 4, 256, 0, stream>>>(offs, csr, h2b, ex2, inv2, b2, out, N);
}

// Round 6
// 344.513 us; speedup vs baseline: 1.5450x; 1.5450x over previous
//
#include <hip/hip_runtime.h>
#include <hip/hip_bf16.h>

#define NEG_SLOPE 0.2f
#define BN_EPS 1e-5f

// two-level counting sort for CSR build
#define NBLK 256            // partition blocks for hist/scatter
#define COARSE_SHIFT 10
#define COARSE_NPB 1024     // nodes per coarse bucket (nCoarse = ceil(N/1024) <= 64)

__device__ __forceinline__ float wred_sum(float v) {
    #pragma unroll
    for (int m = 32; m > 0; m >>= 1) v += __shfl_xor(v, m);
    return v;
}
__device__ __forceinline__ float wred_max(float v) {
    #pragma unroll
    for (int m = 32; m > 0; m >>= 1) v = fmaxf(v, __shfl_xor(v, m));
    return v;
}

__device__ __forceinline__ unsigned pack_bf16(float a, float b) {
    __hip_bfloat162 t;
    t.x = __float2bfloat16(a);
    t.y = __float2bfloat16(b);
    return *(unsigned*)&t;
}
__device__ __forceinline__ float2 unpack_bf16(unsigned u) {
    __hip_bfloat162 t = *(__hip_bfloat162*)&u;
    return {__bfloat162float(t.x), __bfloat162float(t.y)};
}

// ---------------- per-node degree histogram ----------------
__global__ void hist_kernel(const int* __restrict__ ei, int E, int Et, int* __restrict__ deg) {
    int idx = blockIdx.x * blockDim.x + threadIdx.x;
    if (idx >= Et) return;
    int d = (idx < E) ? ei[E + idx] : (idx - E);
    atomicAdd(&deg[d], 1);
}

#define SCAN_CHUNK 2048

__global__ __launch_bounds__(256) void scan_blocksum(const int* __restrict__ deg,
                                                     int* __restrict__ bsum, int n) {
    __shared__ int red[256];
    int b = blockIdx.x, t = threadIdx.x;
    int base = b * SCAN_CHUNK + t * 8;
    int s = 0;
    #pragma unroll
    for (int i = 0; i < 8; ++i) { int idx = base + i; if (idx < n) s += deg[idx]; }
    red[t] = s;
    __syncthreads();
    for (int off = 128; off > 0; off >>= 1) {
        if (t < off) red[t] += red[t + off];
        __syncthreads();
    }
    if (t == 0) bsum[b] = red[0];
}

__global__ __launch_bounds__(1024) void scan_bsums(const int* __restrict__ bsum,
                                                   int* __restrict__ bpre, int nb) {
    __shared__ int s[1024];
    int t = threadIdx.x;
    int v = (t < nb) ? bsum[t] : 0;
    s[t] = v;
    __syncthreads();
    for (int off = 1; off < 1024; off <<= 1) {
        int u = (t >= off) ? s[t - off] : 0;
        __syncthreads();
        s[t] += u;
        __syncthreads();
    }
    if (t < nb) bpre[t] = s[t] - v;
    if (t == 1023) bpre[nb] = s[1023];
}

__global__ __launch_bounds__(256) void scan_scatter(const int* __restrict__ deg,
                                                    const int* __restrict__ bpre,
                                                    int* __restrict__ offs,
                                                    int n, int nb) {
    __shared__ int red[256];
    int b = blockIdx.x, t = threadIdx.x;
    int base = b * SCAN_CHUNK + t * 8;
    int loc[8];
    int s = 0;
    #pragma unroll
    for (int i = 0; i < 8; ++i) {
        int idx = base + i;
        int d = (idx < n) ? deg[idx] : 0;
        loc[i] = s;
        s += d;
    }
    red[t] = s;
    __syncthreads();
    int v = s;
    for (int off = 1; off < 256; off <<= 1) {
        int u = (t >= off) ? red[t - off] : 0;
        __syncthreads();
        red[t] += u;
        __syncthreads();
    }
    int tpre = red[t] - v + bpre[b];
    #pragma unroll
    for (int i = 0; i < 8; ++i) {
        int idx = base + i;
        if (idx < n) offs[idx] = tpre + loc[i];
    }
    if (b == 0 && t == 0) offs[n] = bpre[nb];
}

// ---- stage 1a: per-block coarse histogram (LDS-privatized, no global atomics) ----
__global__ __launch_bounds__(256) void part_hist(const int* __restrict__ ei, int E, int Et,
                                                 int chunk, int* __restrict__ hist, int nCoarse) {
    __shared__ int h[64];
    int b = blockIdx.x, t = threadIdx.x;
    if (t < 64) h[t] = 0;
    __syncthreads();
    int beg = b * chunk, end = min(beg + chunk, Et);
    for (int idx = beg + t; idx < end; idx += 256) {
        int d = (idx < E) ? ei[E + idx] : (idx - E);
        atomicAdd(&h[d >> COARSE_SHIFT], 1);
    }
    __syncthreads();
    if (t < nCoarse) hist[t * NBLK + b] = h[t];
}

// ---- stage 1b: per-bucket exclusive scan over the NBLK block counts ----
__global__ __launch_bounds__(64) void part_scan(int* __restrict__ hist,
                                                const int* __restrict__ offs, int nCoarse) {
    int c = blockIdx.x, t = threadIdx.x;   // 64 threads, 4 entries each
    int base = offs[c << COARSE_SHIFT];
    int idx = c * NBLK + 4 * t;
    int4 v = *(int4*)&hist[idx];
    int sl = v.x + v.y + v.z + v.w;
    int inc = sl;
    #pragma unroll
    for (int off = 1; off < 64; off <<= 1) {
        int u = __shfl_up(inc, off);
        if (t >= off) inc += u;
    }
    int exc = inc - sl + base;
    int4 o;
    o.x = exc;
    o.y = exc + v.x;
    o.z = exc + v.x + v.y;
    o.w = exc + v.x + v.y + v.z;
    *(int4*)&hist[idx] = o;
}

// ---- stage 1c: scatter into coarse-sorted staging (LDS cursors, private slices) ----
__global__ __launch_bounds__(256) void part_scatter(const int* __restrict__ ei, int E, int Et,
                                                    int chunk, const int* __restrict__ hist,
                                                    unsigned* __restrict__ staged, int nCoarse) {
    __shared__ int cur[64];
    int b = blockIdx.x, t = threadIdx.x;
    if (t < nCoarse) cur[t] = hist[t * NBLK + b];
    __syncthreads();
    int beg = b * chunk, end = min(beg + chunk, Et);
    for (int idx = beg + t; idx < end; idx += 256) {
        int s, d;
        if (idx < E) { s = ei[idx]; d = ei[E + idx]; }
        else         { s = idx - E; d = idx - E; }
        int c = d >> COARSE_SHIFT;
        int pos = atomicAdd(&cur[c], 1);
        staged[pos] = ((unsigned)s << COARSE_SHIFT) | (unsigned)(d & (COARSE_NPB - 1));
    }
}

// ---- stage 2: exact placement within each coarse bucket (1024 LDS cursors) ----
__global__ __launch_bounds__(1024) void fine_place(const unsigned* __restrict__ staged,
                                                   const int* __restrict__ offs,
                                                   int* __restrict__ csr, int Nn, int nCoarse) {
    __shared__ int cur[COARSE_NPB];
    int b = blockIdx.x, t = threadIdx.x;
    int node0 = b << COARSE_SHIFT;
    int nloc = min(COARSE_NPB, Nn - node0);
    if (t < nloc) cur[t] = offs[node0 + t];
    __syncthreads();
    int ebeg = offs[node0];
    int eend = offs[node0 + nloc];
    for (int p = ebeg + t; p < eend; p += 1024) {
        unsigned v = staged[p];
        int s  = (int)(v >> COARSE_SHIFT);
        int dl = (int)(v & (COARSE_NPB - 1));
        int pos = atomicAdd(&cur[dl], 1);
        csr[pos] = s;
    }
}

// ---------------- Layer 1 GEMM + fused al1, bf16-packed output ----------------
__global__ __launch_bounds__(256) void gemm1_tiled(const float* __restrict__ x,
                                                   const float* __restrict__ W,
                                                   const float* __restrict__ a1s,
                                                   const float* __restrict__ a1d,
                                                   unsigned* __restrict__ h1b,
                                                   float* __restrict__ als,
                                                   float* __restrict__ ald, int Nn) {
    __shared__ float As[64][33];
    __shared__ float Bs[32][132];
    __shared__ float4 red4[64][17];
    int t  = threadIdx.x;
    int tx = t & 15;
    int ty = t >> 4;
    int br = blockIdx.x * 64;

    float acc[4][8];
    #pragma unroll
    for (int i = 0; i < 4; ++i)
        #pragma unroll
        for (int j = 0; j < 8; ++j) acc[i][j] = 0.f;

    int k4  = t & 7;
    int rowA = t >> 3;

    for (int k0 = 0; k0 < 128; k0 += 32) {
        #pragma unroll
        for (int i = 0; i < 2; ++i) {
            int r  = rowA + 32 * i;
            int gr = min(br + r, Nn - 1);
            float4 v = *(const float4*)(x + (size_t)gr * 128 + k0 + 4 * k4);
            As[r][4 * k4 + 0] = v.x; As[r][4 * k4 + 1] = v.y;
            As[r][4 * k4 + 2] = v.z; As[r][4 * k4 + 3] = v.w;
        }
        #pragma unroll
        for (int i = 0; i < 4; ++i) {
            int f  = t + 256 * i;
            int kk = f >> 5, c4 = f & 31;
            *(float4*)&Bs[kk][4 * c4] = *(const float4*)(W + (size_t)(k0 + kk) * 128 + 4 * c4);
        }
        __syncthreads();
        #pragma unroll
        for (int kk = 0; kk < 32; ++kk) {
            float4 b0 = *(const float4*)&Bs[kk][4 * tx];
            float4 b1 = *(const float4*)&Bs[kk][64 + 4 * tx];
            #pragma unroll
            for (int i = 0; i < 4; ++i) {
                float a = As[4 * ty + i][kk];
                acc[i][0] += a * b0.x; acc[i][1] += a * b0.y;
                acc[i][2] += a * b0.z; acc[i][3] += a * b0.w;
                acc[i][4] += a * b1.x; acc[i][5] += a * b1.y;
                acc[i][6] += a * b1.z; acc[i][7] += a * b1.w;
            }
        }
        __syncthreads();
    }
    float s_lo[4], s_hi[4], d_lo[4], d_hi[4];
    #pragma unroll
    for (int j = 0; j < 4; ++j) {
        s_lo[j] = a1s[4 * tx + j];      s_hi[j] = a1s[64 + 4 * tx + j];
        d_lo[j] = a1d[4 * tx + j];      d_hi[j] = a1d[64 + 4 * tx + j];
    }
    #pragma unroll
    for (int i = 0; i < 4; ++i) {
        float4 pp = {0.f, 0.f, 0.f, 0.f};
        #pragma unroll
        for (int j = 0; j < 4; ++j) {
            pp.x += acc[i][j] * s_lo[j];
            pp.y += acc[i][4 + j] * s_hi[j];
            pp.z += acc[i][j] * d_lo[j];
            pp.w += acc[i][4 + j] * d_hi[j];
        }
        red4[4 * ty + i][tx] = pp;
        int r = br + 4 * ty + i;
        if (r < Nn) {
            uint2 lo = {pack_bf16(acc[i][0], acc[i][1]), pack_bf16(acc[i][2], acc[i][3])};
            uint2 hi = {pack_bf16(acc[i][4], acc[i][5]), pack_bf16(acc[i][6], acc[i][7])};
            *(uint2*)(h1b + (size_t)r * 64 + 2 * tx)      = lo;
            *(uint2*)(h1b + (size_t)r * 64 + 32 + 2 * tx) = hi;
        }
    }
    __syncthreads();
    if (t < 64) {
        int r = br + t;
        if (r < Nn) {
            float4 s = {0.f, 0.f, 0.f, 0.f};
            #pragma unroll
            for (int xx = 0; xx < 16; ++xx) {
                float4 p = red4[t][xx];
                s.x += p.x; s.y += p.y; s.z += p.z; s.w += p.w;
            }
            als[r * 2] = s.x; als[r * 2 + 1] = s.y;
            ald[r * 2] = s.z; ald[r * 2 + 1] = s.w;
        }
    }
}

// ---------------- per-node edge softmax, 2-pass: store unnormalized exp + 1/s ----------------
template <int H>
__global__ void edge_softmax_kernel(const int* __restrict__ offs, const int* __restrict__ csr,
                                    const float* __restrict__ als, const float* __restrict__ ald,
                                    float* __restrict__ lg, float* __restrict__ invs, int Nn) {
    int wid = threadIdx.x >> 6, lane = threadIdx.x & 63;
    int n = blockIdx.x * 4 + wid;
    if (n >= Nn) return;
    int b = offs[n], e = offs[n + 1];
    float aldn[H];
    #pragma unroll
    for (int h = 0; h < H; ++h) aldn[h] = ald[n * H + h];
    float mx[H];
    #pragma unroll
    for (int h = 0; h < H; ++h) mx[h] = -1e30f;
    for (int p = b + lane; p < e; p += 64) {
        int s = csr[p];
        #pragma unroll
        for (int h = 0; h < H; ++h) {
            float l = als[s * H + h] + aldn[h];
            l = (l > 0.f) ? l : NEG_SLOPE * l;
            lg[p * H + h] = l;
            mx[h] = fmaxf(mx[h], l);
        }
    }
    #pragma unroll
    for (int h = 0; h < H; ++h) mx[h] = wred_max(mx[h]);
    float sm[H];
    #pragma unroll
    for (int h = 0; h < H; ++h) sm[h] = 0.f;
    for (int p = b + lane; p < e; p += 64) {
        #pragma unroll
        for (int h = 0; h < H; ++h) {
            float t = expf(lg[p * H + h] - mx[h]);
            lg[p * H + h] = t;
            sm[h] += t;
        }
    }
    #pragma unroll
    for (int h = 0; h < H; ++h) sm[h] = wred_sum(sm[h]);
    if (lane == 0) {
        #pragma unroll
        for (int h = 0; h < H; ++h) invs[n * H + h] = 1.f / (sm[h] + 1e-16f);
    }
}

// ---------------- layer-1 aggregation: bf16 gather, 4 edges in flight ----------------
__global__ __launch_bounds__(256) void agg1_kernel(const int* __restrict__ offs, const int* __restrict__ csr,
                            const unsigned* __restrict__ h1b, const float* __restrict__ ex,
                            const float* __restrict__ invs,
                            const float* __restrict__ b1, const float* __restrict__ gam,
                            const float* __restrict__ bet, const float* __restrict__ mean,
                            const float* __restrict__ var, float* __restrict__ hbn, int Nn) {
    int wid = threadIdx.x >> 6, lane = threadIdx.x & 63;
    int n = blockIdx.x * 4 + wid;
    if (n >= Nn) return;
    int sub = lane >> 4;
    int l16 = lane & 15;
    int head = l16 >> 3;
    int b = offs[n], e = offs[n + 1];
    float acc[8];
    #pragma unroll
    for (int j = 0; j < 8; ++j) acc[j] = 0.f;
    for (int p = b + sub; p < e; p += 4) {
        int s = csr[p];
        float a = ex[p * 2 + head];
        uint4 v = *(const uint4*)(h1b + (size_t)s * 64 + 4 * l16);
        float2 f0 = unpack_bf16(v.x), f1 = unpack_bf16(v.y);
        float2 f2 = unpack_bf16(v.z), f3 = unpack_bf16(v.w);
        acc[0] += f0.x * a; acc[1] += f0.y * a;
        acc[2] += f1.x * a; acc[3] += f1.y * a;
        acc[4] += f2.x * a; acc[5] += f2.y * a;
        acc[6] += f3.x * a; acc[7] += f3.y * a;
    }
    #pragma unroll
    for (int j = 0; j < 8; ++j) {
        acc[j] += __shfl_xor(acc[j], 16);
        acc[j] += __shfl_xor(acc[j], 32);
    }
    if (sub == 0) {
        float inv = invs[n * 2 + head];
        int c = 8 * l16;
        #pragma unroll
        for (int half = 0; half < 2; ++half) {
            int cc = c + 4 * half;
            float4 bb = *(const float4*)(b1 + cc);
            float4 gg = *(const float4*)(gam + cc);
            float4 be = *(const float4*)(bet + cc);
            float4 mm = *(const float4*)(mean + cc);
            float4 vv = *(const float4*)(var + cc);
            float4 o;
            o.x = fmaxf((acc[4*half+0] * inv + bb.x - mm.x) * rsqrtf(vv.x + BN_EPS) * gg.x + be.x, 0.f);
            o.y = fmaxf((acc[4*half+1] * inv + bb.y - mm.y) * rsqrtf(vv.y + BN_EPS) * gg.y + be.y, 0.f);
            o.z = fmaxf((acc[4*half+2] * inv + bb.z - mm.z) * rsqrtf(vv.z + BN_EPS) * gg.z + be.z, 0.f);
            o.w = fmaxf((acc[4*half+3] * inv + bb.w - mm.w) * rsqrtf(vv.w + BN_EPS) * gg.w + be.w, 0.f);
            *(float4*)(hbn + (size_t)n * 128 + cc) = o;
        }
    }
}

// ---------------- layer 2 GEMM tiled + fused al2, bf16-packed output ----------------
__global__ __launch_bounds__(256) void gemm2_tiled(const float* __restrict__ hbn,
                                                   const float* __restrict__ W2,
                                                   const float* __restrict__ a2s,
                                                   const float* __restrict__ a2d,
                                                   unsigned* __restrict__ h2b,
                                                   float* __restrict__ als, float* __restrict__ ald,
                                                   int Nn) {
    __shared__ float As[64][33];
    __shared__ float Bs[128][68];
    __shared__ float redS[64][17];
    __shared__ float redD[64][17];
    int t  = threadIdx.x;
    int tx = t & 15;
    int ty = t >> 4;
    int br = blockIdx.x * 64;

    #pragma unroll
    for (int i = 0; i < 8; ++i) {
        int f  = t + 256 * i;
        int kk = f >> 4, c4 = f & 15;
        float4 v = {0.f, 0.f, 0.f, 0.f};
        if (c4 < 10) v = *(const float4*)(W2 + (size_t)kk * 40 + 4 * c4);
        *(float4*)&Bs[kk][4 * c4] = v;
    }
    float as4[4], ad4[4];
    #pragma unroll
    for (int j = 0; j < 4; ++j) {
        int c = 4 * tx + j;
        as4[j] = (c < 40) ? a2s[c] : 0.f;
        ad4[j] = (c < 40) ? a2d[c] : 0.f;
    }

    float acc[4][4];
    #pragma unroll
    for (int i = 0; i < 4; ++i)
        #pragma unroll
        for (int j = 0; j < 4; ++j) acc[i][j] = 0.f;

    int k4  = t & 7;
    int rowA = t >> 3;
    __syncthreads();

    for (int k0 = 0; k0 < 128; k0 += 32) {
        #pragma unroll
        for (int i = 0; i < 2; ++i) {
            int r  = rowA + 32 * i;
            int gr = min(br + r, Nn - 1);
            float4 v = *(const float4*)(hbn + (size_t)gr * 128 + k0 + 4 * k4);
            As[r][4 * k4 + 0] = v.x; As[r][4 * k4 + 1] = v.y;
            As[r][4 * k4 + 2] = v.z; As[r][4 * k4 + 3] = v.w;
        }
        __syncthreads();
        #pragma unroll
        for (int kk = 0; kk < 32; ++kk) {
            float4 b0 = *(const float4*)&Bs[k0 + kk][4 * tx];
            #pragma unroll
            for (int i = 0; i < 4; ++i) {
                float a = As[4 * ty + i][kk];
                acc[i][0] += a * b0.x; acc[i][1] += a * b0.y;
                acc[i][2] += a * b0.z; acc[i][3] += a * b0.w;
            }
        }
        __syncthreads();
    }
    #pragma unroll
    for (int i = 0; i < 4; ++i) {
        redS[4 * ty + i][tx] = acc[i][0] * as4[0] + acc[i][1] * as4[1] + acc[i][2] * as4[2] + acc[i][3] * as4[3];
        redD[4 * ty + i][tx] = acc[i][0] * ad4[0] + acc[i][1] * ad4[1] + acc[i][2] * ad4[2] + acc[i][3] * ad4[3];
        int r = br + 4 * ty + i;
        if (r < Nn) {
            uint2 pk = {pack_bf16(acc[i][0], acc[i][1]), pack_bf16(acc[i][2], acc[i][3])};
            *(uint2*)(h2b + (size_t)r * 32 + 2 * tx) = pk;
        }
    }
    __syncthreads();
    if (t < 64) {
        int r = br + t;
        if (r < Nn) {
            float sS = 0.f, sD = 0.f;
            #pragma unroll
            for (int xx = 0; xx < 16; ++xx) { sS += redS[t][xx]; sD += redD[t][xx]; }
            als[r] = sS; ald[r] = sD;
        }
    }
}

// ---------------- layer-2 aggregation: bf16 gather, 4 edges in flight, + log_softmax ----------------
__global__ __launch_bounds__(256) void agg2_kernel(const int* __restrict__ offs, const int* __restrict__ csr,
                            const unsigned* __restrict__ h2b, const float* __restrict__ ex,
                            const float* __restrict__ invs, const float* __restrict__ b2,
                            float* __restrict__ out, int Nn) {
    int wid = threadIdx.x >> 6, lane = threadIdx.x & 63;
    int n = blockIdx.x * 4 + wid;
    if (n >= Nn) return;
    int sub = lane >> 4;
    int l16 = lane & 15;
    int b = offs[n], e = offs[n + 1];
    float acc[4];
    #pragma unroll
    for (int j = 0; j < 4; ++j) acc[j] = 0.f;
    for (int p = b + sub; p < e; p += 4) {
        int s = csr[p];
        float a = ex[p];
        uint2 v = *(const uint2*)(h2b + (size_t)s * 32 + 2 * l16);
        float2 f0 = unpack_bf16(v.x), f1 = unpack_bf16(v.y);
        acc[0] += f0.x * a; acc[1] += f0.y * a;
        acc[2] += f1.x * a; acc[3] += f1.y * a;
    }
    #pragma unroll
    for (int j = 0; j < 4; ++j) {
        acc[j] += __shfl_xor(acc[j], 16);
        acc[j] += __shfl_xor(acc[j], 32);
    }
    float inv = invs[n];
    bool valid = (l16 < 10);
    float v0 = -1e30f, v1 = -1e30f, v2 = -1e30f, v3 = -1e30f;
    if (valid) {
        int c = 4 * l16;
        v0 = acc[0] * inv + b2[c];
        v1 = acc[1] * inv + b2[c + 1];
        v2 = acc[2] * inv + b2[c + 2];
        v3 = acc[3] * inv + b2[c + 3];
    }
    float m = wred_max(fmaxf(fmaxf(v0, v1), fmaxf(v2, v3)));
    float es = (valid && sub == 0)
             ? (expf(v0 - m) + expf(v1 - m) + expf(v2 - m) + expf(v3 - m)) : 0.f;
    float ssum = wred_sum(es);
    float lse = m + logf(ssum);
    if (sub == 0 && valid) {
        float4 o = {v0 - lse, v1 - lse, v2 - lse, v3 - lse};
        *(float4*)(out + (size_t)n * 40 + 4 * l16) = o;
    }
}

extern "C" void kernel_launch(void* const* d_in, const int* in_sizes, int n_in,
                              void* d_out, int out_size, void* d_ws, size_t ws_size,
                              hipStream_t stream) {
    const float* x    = (const float*)d_in[0];
    const int*   ei   = (const int*)d_in[1];
    const float* W1   = (const float*)d_in[2];
    const float* a1s  = (const float*)d_in[3];
    const float* a1d  = (const float*)d_in[4];
    const float* b1   = (const float*)d_in[5];
    const float* g1   = (const float*)d_in[6];
    const float* be1  = (const float*)d_in[7];
    const float* mn1  = (const float*)d_in[8];
    const float* vr1  = (const float*)d_in[9];
    const float* W2   = (const float*)d_in[10];
    const float* a2s  = (const float*)d_in[11];
    const float* a2d  = (const float*)d_in[12];
    const float* b2   = (const float*)d_in[13];
    float* out = (float*)d_out;

    const int N  = in_sizes[0] / 128;
    const int E  = in_sizes[1] / 2;
    const int Et = E + N;
    const int nScanB  = (N + SCAN_CHUNK - 1) / SCAN_CHUNK;
    const int nCoarse = (N + COARSE_NPB - 1) >> COARSE_SHIFT;
    const int chunk   = (Et + NBLK - 1) / NBLK;

    char* p = (char*)d_ws;
    auto alloc = [&](size_t bytes) -> void* {
        void* r = (void*)p;
        p += (bytes + 255) & ~(size_t)255;
        return r;
    };
    int*      deg    = (int*)alloc((size_t)N * 4);
    int*      offs   = (int*)alloc((size_t)(N + 1) * 4);
    int*      bsum   = (int*)alloc((size_t)(nScanB + 1) * 4);
    int*      bpre   = (int*)alloc((size_t)(nScanB + 1) * 4);
    int*      hist   = (int*)alloc((size_t)nCoarse * NBLK * 4);
    unsigned* staged = (unsigned*)alloc((size_t)Et * 4);
    int*      csr    = (int*)alloc((size_t)Et * 4);
    unsigned* h1b    = (unsigned*)alloc((size_t)N * 64 * 4);
    float*    al1sv  = (float*)alloc((size_t)N * 2 * 4);
    float*    al1dv  = (float*)alloc((size_t)N * 2 * 4);
    float*    ex1    = (float*)alloc((size_t)Et * 2 * 4);
    float*    inv1   = (float*)alloc((size_t)N * 2 * 4);
    float*    hbn    = (float*)alloc((size_t)N * 128 * 4);
    unsigned* h2b    = (unsigned*)alloc((size_t)N * 32 * 4);
    float*    al2sv  = (float*)alloc((size_t)N * 4);
    float*    al2dv  = (float*)alloc((size_t)N * 4);
    float*    ex2    = (float*)alloc((size_t)Et * 4);
    float*    inv2   = (float*)alloc((size_t)N * 4);
    (void)ws_size;

    hipMemsetAsync(deg, 0, (size_t)N * 4, stream);

    int tpb = 256;
    hist_kernel<<<(Et + tpb - 1) / tpb, tpb, 0, stream>>>(ei, E, Et, deg);
    part_hist<<<NBLK, 256, 0, stream>>>(ei, E, Et, chunk, hist, nCoarse);
    scan_blocksum<<<nScanB, 256, 0, stream>>>(deg, bsum, N);
    scan_bsums<<<1, 1024, 0, stream>>>(bsum, bpre, nScanB);
    scan_scatter<<<nScanB, 256, 0, stream>>>(deg, bpre, offs, N, nScanB);
    part_scan<<<nCoarse, 64, 0, stream>>>(hist, offs, nCoarse);
    part_scatter<<<NBLK, 256, 0, stream>>>(ei, E, Et, chunk, hist, staged, nCoarse);
    fine_place<<<nCoarse, 1024, 0, stream>>>(staged, offs, csr, N, nCoarse);

    gemm1_tiled<<<(N + 63) / 64, 256, 0, stream>>>(x, W1, a1s, a1d, h1b, al1sv, al1dv, N);
    edge_softmax_kernel<2><<<(N + 3) / 4, 256, 0, stream>>>(offs, csr, al1sv, al1dv, ex1, inv1, N);
    agg1_kernel<<<(N + 3) / 4, 256, 0, stream>>>(offs, csr, h1b, ex1, inv1, b1, g1, be1, mn1, vr1, hbn, N);

    gemm2_tiled<<<(N + 63) / 64, 256, 0, stream>>>(hbn, W2, a2s, a2d, h2b, al2sv, al2dv, N);
    edge_softmax_kernel<1><<<(N + 3) / 4, 256, 0, stream>>>(offs, csr, al2sv, al2dv, ex2, inv2, N);
    agg2_kernel<<<(N + 3) / 4, 256, 0, stream>>>(offs, csr, h2b, ex2, inv2, b2, out, N);
}

// Round 7
// 319.017 us; speedup vs baseline: 1.6685x; 1.0799x over previous
//
#include <hip/hip_runtime.h>
#include <hip/hip_bf16.h>

#define NEG_SLOPE 0.2f
#define BN_EPS 1e-5f

// two-level counting sort for CSR build
#define NBLK 256
#define COARSE_SHIFT 10
#define COARSE_NPB 1024

__device__ __forceinline__ float wred_sum(float v) {
    #pragma unroll
    for (int m = 32; m > 0; m >>= 1) v += __shfl_xor(v, m);
    return v;
}
__device__ __forceinline__ float wred_max(float v) {
    #pragma unroll
    for (int m = 32; m > 0; m >>= 1) v = fmaxf(v, __shfl_xor(v, m));
    return v;
}

__device__ __forceinline__ unsigned pack_bf16(float a, float b) {
    __hip_bfloat162 t;
    t.x = __float2bfloat16(a);
    t.y = __float2bfloat16(b);
    return *(unsigned*)&t;
}
__device__ __forceinline__ float2 unpack_bf16(unsigned u) {
    __hip_bfloat162 t = *(__hip_bfloat162*)&u;
    return {__bfloat162float(t.x), __bfloat162float(t.y)};
}

// ---- fused: per-node degree histogram + per-block coarse histogram (one ei pass) ----
__global__ __launch_bounds__(256) void hist_fused(const int* __restrict__ ei, int E, int Et,
                                                  int chunk, int* __restrict__ deg,
                                                  int* __restrict__ hist, int nCoarse) {
    __shared__ int h[64];
    int b = blockIdx.x, t = threadIdx.x;
    if (t < 64) h[t] = 0;
    __syncthreads();
    int beg = b * chunk, end = min(beg + chunk, Et);
    for (int idx = beg + t; idx < end; idx += 256) {
        int d = (idx < E) ? ei[E + idx] : (idx - E);
        atomicAdd(&deg[d], 1);
        atomicAdd(&h[d >> COARSE_SHIFT], 1);
    }
    __syncthreads();
    if (t < nCoarse) hist[t * NBLK + b] = h[t];
}

#define SCAN_CHUNK 2048

__global__ __launch_bounds__(256) void scan_blocksum(const int* __restrict__ deg,
                                                     int* __restrict__ bsum, int n) {
    __shared__ int red[256];
    int b = blockIdx.x, t = threadIdx.x;
    int base = b * SCAN_CHUNK + t * 8;
    int s = 0;
    #pragma unroll
    for (int i = 0; i < 8; ++i) { int idx = base + i; if (idx < n) s += deg[idx]; }
    red[t] = s;
    __syncthreads();
    for (int off = 128; off > 0; off >>= 1) {
        if (t < off) red[t] += red[t + off];
        __syncthreads();
    }
    if (t == 0) bsum[b] = red[0];
}

__global__ __launch_bounds__(1024) void scan_bsums(const int* __restrict__ bsum,
                                                   int* __restrict__ bpre, int nb) {
    __shared__ int s[1024];
    int t = threadIdx.x;
    int v = (t < nb) ? bsum[t] : 0;
    s[t] = v;
    __syncthreads();
    for (int off = 1; off < 1024; off <<= 1) {
        int u = (t >= off) ? s[t - off] : 0;
        __syncthreads();
        s[t] += u;
        __syncthreads();
    }
    if (t < nb) bpre[t] = s[t] - v;
    if (t == 1023) bpre[nb] = s[1023];
}

__global__ __launch_bounds__(256) void scan_scatter(const int* __restrict__ deg,
                                                    const int* __restrict__ bpre,
                                                    int* __restrict__ offs,
                                                    int n, int nb) {
    __shared__ int red[256];
    int b = blockIdx.x, t = threadIdx.x;
    int base = b * SCAN_CHUNK + t * 8;
    int loc[8];
    int s = 0;
    #pragma unroll
    for (int i = 0; i < 8; ++i) {
        int idx = base + i;
        int d = (idx < n) ? deg[idx] : 0;
        loc[i] = s;
        s += d;
    }
    red[t] = s;
    __syncthreads();
    int v = s;
    for (int off = 1; off < 256; off <<= 1) {
        int u = (t >= off) ? red[t - off] : 0;
        __syncthreads();
        red[t] += u;
        __syncthreads();
    }
    int tpre = red[t] - v + bpre[b];
    #pragma unroll
    for (int i = 0; i < 8; ++i) {
        int idx = base + i;
        if (idx < n) offs[idx] = tpre + loc[i];
    }
    if (b == 0 && t == 0) offs[n] = bpre[nb];
}

__global__ __launch_bounds__(64) void part_scan(int* __restrict__ hist,
                                                const int* __restrict__ offs, int nCoarse) {
    int c = blockIdx.x, t = threadIdx.x;
    int base = offs[c << COARSE_SHIFT];
    int idx = c * NBLK + 4 * t;
    int4 v = *(int4*)&hist[idx];
    int sl = v.x + v.y + v.z + v.w;
    int inc = sl;
    #pragma unroll
    for (int off = 1; off < 64; off <<= 1) {
        int u = __shfl_up(inc, off);
        if (t >= off) inc += u;
    }
    int exc = inc - sl + base;
    int4 o;
    o.x = exc;
    o.y = exc + v.x;
    o.z = exc + v.x + v.y;
    o.w = exc + v.x + v.y + v.z;
    *(int4*)&hist[idx] = o;
}

__global__ __launch_bounds__(256) void part_scatter(const int* __restrict__ ei, int E, int Et,
                                                    int chunk, const int* __restrict__ hist,
                                                    unsigned* __restrict__ staged, int nCoarse) {
    __shared__ int cur[64];
    int b = blockIdx.x, t = threadIdx.x;
    if (t < nCoarse) cur[t] = hist[t * NBLK + b];
    __syncthreads();
    int beg = b * chunk, end = min(beg + chunk, Et);
    for (int idx = beg + t; idx < end; idx += 256) {
        int s, d;
        if (idx < E) { s = ei[idx]; d = ei[E + idx]; }
        else         { s = idx - E; d = idx - E; }
        int c = d >> COARSE_SHIFT;
        int pos = atomicAdd(&cur[c], 1);
        staged[pos] = ((unsigned)s << COARSE_SHIFT) | (unsigned)(d & (COARSE_NPB - 1));
    }
}

__global__ __launch_bounds__(1024) void fine_place(const unsigned* __restrict__ staged,
                                                   const int* __restrict__ offs,
                                                   int* __restrict__ csr, int Nn, int nCoarse) {
    __shared__ int cur[COARSE_NPB];
    int b = blockIdx.x, t = threadIdx.x;
    int node0 = b << COARSE_SHIFT;
    int nloc = min(COARSE_NPB, Nn - node0);
    if (t < nloc) cur[t] = offs[node0 + t];
    __syncthreads();
    int ebeg = offs[node0];
    int eend = offs[node0 + nloc];
    for (int p = ebeg + t; p < eend; p += 1024) {
        unsigned v = staged[p];
        int s  = (int)(v >> COARSE_SHIFT);
        int dl = (int)(v & (COARSE_NPB - 1));
        int pos = atomicAdd(&cur[dl], 1);
        csr[pos] = s;
    }
}

// ---------------- Layer 1 GEMM + fused al1, bf16-packed output ----------------
__global__ __launch_bounds__(256) void gemm1_tiled(const float* __restrict__ x,
                                                   const float* __restrict__ W,
                                                   const float* __restrict__ a1s,
                                                   const float* __restrict__ a1d,
                                                   unsigned* __restrict__ h1b,
                                                   float* __restrict__ als,
                                                   float* __restrict__ ald, int Nn) {
    __shared__ float As[64][33];
    __shared__ float Bs[32][132];
    __shared__ float4 red4[64][17];
    int t  = threadIdx.x;
    int tx = t & 15;
    int ty = t >> 4;
    int br = blockIdx.x * 64;

    float acc[4][8];
    #pragma unroll
    for (int i = 0; i < 4; ++i)
        #pragma unroll
        for (int j = 0; j < 8; ++j) acc[i][j] = 0.f;

    int k4  = t & 7;
    int rowA = t >> 3;

    for (int k0 = 0; k0 < 128; k0 += 32) {
        #pragma unroll
        for (int i = 0; i < 2; ++i) {
            int r  = rowA + 32 * i;
            int gr = min(br + r, Nn - 1);
            float4 v = *(const float4*)(x + (size_t)gr * 128 + k0 + 4 * k4);
            As[r][4 * k4 + 0] = v.x; As[r][4 * k4 + 1] = v.y;
            As[r][4 * k4 + 2] = v.z; As[r][4 * k4 + 3] = v.w;
        }
        #pragma unroll
        for (int i = 0; i < 4; ++i) {
            int f  = t + 256 * i;
            int kk = f >> 5, c4 = f & 31;
            *(float4*)&Bs[kk][4 * c4] = *(const float4*)(W + (size_t)(k0 + kk) * 128 + 4 * c4);
        }
        __syncthreads();
        #pragma unroll
        for (int kk = 0; kk < 32; ++kk) {
            float4 b0 = *(const float4*)&Bs[kk][4 * tx];
            float4 b1 = *(const float4*)&Bs[kk][64 + 4 * tx];
            #pragma unroll
            for (int i = 0; i < 4; ++i) {
                float a = As[4 * ty + i][kk];
                acc[i][0] += a * b0.x; acc[i][1] += a * b0.y;
                acc[i][2] += a * b0.z; acc[i][3] += a * b0.w;
                acc[i][4] += a * b1.x; acc[i][5] += a * b1.y;
                acc[i][6] += a * b1.z; acc[i][7] += a * b1.w;
            }
        }
        __syncthreads();
    }
    float s_lo[4], s_hi[4], d_lo[4], d_hi[4];
    #pragma unroll
    for (int j = 0; j < 4; ++j) {
        s_lo[j] = a1s[4 * tx + j];      s_hi[j] = a1s[64 + 4 * tx + j];
        d_lo[j] = a1d[4 * tx + j];      d_hi[j] = a1d[64 + 4 * tx + j];
    }
    #pragma unroll
    for (int i = 0; i < 4; ++i) {
        float4 pp = {0.f, 0.f, 0.f, 0.f};
        #pragma unroll
        for (int j = 0; j < 4; ++j) {
            pp.x += acc[i][j] * s_lo[j];
            pp.y += acc[i][4 + j] * s_hi[j];
            pp.z += acc[i][j] * d_lo[j];
            pp.w += acc[i][4 + j] * d_hi[j];
        }
        red4[4 * ty + i][tx] = pp;
        int r = br + 4 * ty + i;
        if (r < Nn) {
            uint2 lo = {pack_bf16(acc[i][0], acc[i][1]), pack_bf16(acc[i][2], acc[i][3])};
            uint2 hi = {pack_bf16(acc[i][4], acc[i][5]), pack_bf16(acc[i][6], acc[i][7])};
            *(uint2*)(h1b + (size_t)r * 64 + 2 * tx)      = lo;
            *(uint2*)(h1b + (size_t)r * 64 + 32 + 2 * tx) = hi;
        }
    }
    __syncthreads();
    if (t < 64) {
        int r = br + t;
        if (r < Nn) {
            float4 s = {0.f, 0.f, 0.f, 0.f};
            #pragma unroll
            for (int xx = 0; xx < 16; ++xx) {
                float4 p = red4[t][xx];
                s.x += p.x; s.y += p.y; s.z += p.z; s.w += p.w;
            }
            als[r * 2] = s.x; als[r * 2 + 1] = s.y;
            ald[r * 2] = s.z; ald[r * 2 + 1] = s.w;
        }
    }
}

// ---------------- fused edge-softmax + aggregation, layer 1 (+ bias+BN+ReLU) ----------------
// wave per node. Pass A: max logits per head. Pass B: accumulate num & den together.
__global__ __launch_bounds__(256) void softagg1_kernel(const int* __restrict__ offs, const int* __restrict__ csr,
                            const unsigned* __restrict__ h1b,
                            const float* __restrict__ als, const float* __restrict__ ald,
                            const float* __restrict__ b1, const float* __restrict__ gam,
                            const float* __restrict__ bet, const float* __restrict__ mean,
                            const float* __restrict__ var, float* __restrict__ hbn, int Nn) {
    int wid = threadIdx.x >> 6, lane = threadIdx.x & 63;
    int n = blockIdx.x * 4 + wid;
    if (n >= Nn) return;
    int b = offs[n], e = offs[n + 1];
    float ald0 = ald[n * 2], ald1 = ald[n * 2 + 1];

    // pass A: per-head max of leaky_relu(als[s] + ald[n]) — 64 edges in flight
    float mx0 = -1e30f, mx1 = -1e30f;
    for (int p = b + lane; p < e; p += 64) {
        int s = csr[p];
        float2 as = *(const float2*)(als + s * 2);
        float l0 = as.x + ald0; l0 = (l0 > 0.f) ? l0 : NEG_SLOPE * l0;
        float l1 = as.y + ald1; l1 = (l1 > 0.f) ? l1 : NEG_SLOPE * l1;
        mx0 = fmaxf(mx0, l0); mx1 = fmaxf(mx1, l1);
    }
    mx0 = wred_max(mx0); mx1 = wred_max(mx1);

    // pass B: 4 edges in flight; each 16-lane group does one full 256 B row
    int sub = lane >> 4;
    int l16 = lane & 15;
    int head = l16 >> 3;
    float mxh  = head ? mx1 : mx0;
    float aldh = head ? ald1 : ald0;
    float acc[8];
    #pragma unroll
    for (int j = 0; j < 8; ++j) acc[j] = 0.f;
    float den = 0.f;
    for (int p = b + sub; p < e; p += 4) {
        int s = csr[p];
        float al = als[s * 2 + head] + aldh;
        al = (al > 0.f) ? al : NEG_SLOPE * al;
        float ev = __expf(al - mxh);
        uint4 v = *(const uint4*)(h1b + (size_t)s * 64 + 4 * l16);
        float2 f0 = unpack_bf16(v.x), f1 = unpack_bf16(v.y);
        float2 f2 = unpack_bf16(v.z), f3 = unpack_bf16(v.w);
        acc[0] += f0.x * ev; acc[1] += f0.y * ev;
        acc[2] += f1.x * ev; acc[3] += f1.y * ev;
        acc[4] += f2.x * ev; acc[5] += f2.y * ev;
        acc[6] += f3.x * ev; acc[7] += f3.y * ev;
        den += ev;
    }
    #pragma unroll
    for (int j = 0; j < 8; ++j) {
        acc[j] += __shfl_xor(acc[j], 16);
        acc[j] += __shfl_xor(acc[j], 32);
    }
    den += __shfl_xor(den, 16);
    den += __shfl_xor(den, 32);
    if (sub == 0) {
        float inv = 1.f / (den + 1e-16f);
        int c = 8 * l16;
        #pragma unroll
        for (int half = 0; half < 2; ++half) {
            int cc = c + 4 * half;
            float4 bb = *(const float4*)(b1 + cc);
            float4 gg = *(const float4*)(gam + cc);
            float4 be = *(const float4*)(bet + cc);
            float4 mm = *(const float4*)(mean + cc);
            float4 vv = *(const float4*)(var + cc);
            float4 o;
            o.x = fmaxf((acc[4*half+0] * inv + bb.x - mm.x) * rsqrtf(vv.x + BN_EPS) * gg.x + be.x, 0.f);
            o.y = fmaxf((acc[4*half+1] * inv + bb.y - mm.y) * rsqrtf(vv.y + BN_EPS) * gg.y + be.y, 0.f);
            o.z = fmaxf((acc[4*half+2] * inv + bb.z - mm.z) * rsqrtf(vv.z + BN_EPS) * gg.z + be.z, 0.f);
            o.w = fmaxf((acc[4*half+3] * inv + bb.w - mm.w) * rsqrtf(vv.w + BN_EPS) * gg.w + be.w, 0.f);
            *(float4*)(hbn + (size_t)n * 128 + cc) = o;
        }
    }
}

// ---------------- layer 2 GEMM tiled + fused al2, bf16-packed output ----------------
__global__ __launch_bounds__(256) void gemm2_tiled(const float* __restrict__ hbn,
                                                   const float* __restrict__ W2,
                                                   const float* __restrict__ a2s,
                                                   const float* __restrict__ a2d,
                                                   unsigned* __restrict__ h2b,
                                                   float* __restrict__ als, float* __restrict__ ald,
                                                   int Nn) {
    __shared__ float As[64][33];
    __shared__ float Bs[128][68];
    __shared__ float redS[64][17];
    __shared__ float redD[64][17];
    int t  = threadIdx.x;
    int tx = t & 15;
    int ty = t >> 4;
    int br = blockIdx.x * 64;

    #pragma unroll
    for (int i = 0; i < 8; ++i) {
        int f  = t + 256 * i;
        int kk = f >> 4, c4 = f & 15;
        float4 v = {0.f, 0.f, 0.f, 0.f};
        if (c4 < 10) v = *(const float4*)(W2 + (size_t)kk * 40 + 4 * c4);
        *(float4*)&Bs[kk][4 * c4] = v;
    }
    float as4[4], ad4[4];
    #pragma unroll
    for (int j = 0; j < 4; ++j) {
        int c = 4 * tx + j;
        as4[j] = (c < 40) ? a2s[c] : 0.f;
        ad4[j] = (c < 40) ? a2d[c] : 0.f;
    }

    float acc[4][4];
    #pragma unroll
    for (int i = 0; i < 4; ++i)
        #pragma unroll
        for (int j = 0; j < 4; ++j) acc[i][j] = 0.f;

    int k4  = t & 7;
    int rowA = t >> 3;
    __syncthreads();

    for (int k0 = 0; k0 < 128; k0 += 32) {
        #pragma unroll
        for (int i = 0; i < 2; ++i) {
            int r  = rowA + 32 * i;
            int gr = min(br + r, Nn - 1);
            float4 v = *(const float4*)(hbn + (size_t)gr * 128 + k0 + 4 * k4);
            As[r][4 * k4 + 0] = v.x; As[r][4 * k4 + 1] = v.y;
            As[r][4 * k4 + 2] = v.z; As[r][4 * k4 + 3] = v.w;
        }
        __syncthreads();
        #pragma unroll
        for (int kk = 0; kk < 32; ++kk) {
            float4 b0 = *(const float4*)&Bs[k0 + kk][4 * tx];
            #pragma unroll
            for (int i = 0; i < 4; ++i) {
                float a = As[4 * ty + i][kk];
                acc[i][0] += a * b0.x; acc[i][1] += a * b0.y;
                acc[i][2] += a * b0.z; acc[i][3] += a * b0.w;
            }
        }
        __syncthreads();
    }
    #pragma unroll
    for (int i = 0; i < 4; ++i) {
        redS[4 * ty + i][tx] = acc[i][0] * as4[0] + acc[i][1] * as4[1] + acc[i][2] * as4[2] + acc[i][3] * as4[3];
        redD[4 * ty + i][tx] = acc[i][0] * ad4[0] + acc[i][1] * ad4[1] + acc[i][2] * ad4[2] + acc[i][3] * ad4[3];
        int r = br + 4 * ty + i;
        if (r < Nn) {
            uint2 pk = {pack_bf16(acc[i][0], acc[i][1]), pack_bf16(acc[i][2], acc[i][3])};
            *(uint2*)(h2b + (size_t)r * 32 + 2 * tx) = pk;
        }
    }
    __syncthreads();
    if (t < 64) {
        int r = br + t;
        if (r < Nn) {
            float sS = 0.f, sD = 0.f;
            #pragma unroll
            for (int xx = 0; xx < 16; ++xx) { sS += redS[t][xx]; sD += redD[t][xx]; }
            als[r] = sS; ald[r] = sD;
        }
    }
}

// ---------------- fused edge-softmax + aggregation, layer 2 (+ bias + log_softmax) ----------------
__global__ __launch_bounds__(256) void softagg2_kernel(const int* __restrict__ offs, const int* __restrict__ csr,
                            const unsigned* __restrict__ h2b,
                            const float* __restrict__ als, const float* __restrict__ ald,
                            const float* __restrict__ b2,
                            float* __restrict__ out, int Nn) {
    int wid = threadIdx.x >> 6, lane = threadIdx.x & 63;
    int n = blockIdx.x * 4 + wid;
    if (n >= Nn) return;
    int b = offs[n], e = offs[n + 1];
    float aldn = ald[n];

    float mx = -1e30f;
    for (int p = b + lane; p < e; p += 64) {
        int s = csr[p];
        float l = als[s] + aldn;
        l = (l > 0.f) ? l : NEG_SLOPE * l;
        mx = fmaxf(mx, l);
    }
    mx = wred_max(mx);

    int sub = lane >> 4;
    int l16 = lane & 15;
    float acc[4];
    #pragma unroll
    for (int j = 0; j < 4; ++j) acc[j] = 0.f;
    float den = 0.f;
    for (int p = b + sub; p < e; p += 4) {
        int s = csr[p];
        float l = als[s] + aldn;
        l = (l > 0.f) ? l : NEG_SLOPE * l;
        float ev = __expf(l - mx);
        uint2 v = *(const uint2*)(h2b + (size_t)s * 32 + 2 * l16);
        float2 f0 = unpack_bf16(v.x), f1 = unpack_bf16(v.y);
        acc[0] += f0.x * ev; acc[1] += f0.y * ev;
        acc[2] += f1.x * ev; acc[3] += f1.y * ev;
        den += ev;
    }
    #pragma unroll
    for (int j = 0; j < 4; ++j) {
        acc[j] += __shfl_xor(acc[j], 16);
        acc[j] += __shfl_xor(acc[j], 32);
    }
    den += __shfl_xor(den, 16);
    den += __shfl_xor(den, 32);
    float inv = 1.f / (den + 1e-16f);
    bool valid = (l16 < 10);
    float v0 = -1e30f, v1 = -1e30f, v2 = -1e30f, v3 = -1e30f;
    if (valid) {
        int c = 4 * l16;
        v0 = acc[0] * inv + b2[c];
        v1 = acc[1] * inv + b2[c + 1];
        v2 = acc[2] * inv + b2[c + 2];
        v3 = acc[3] * inv + b2[c + 3];
    }
    float m = wred_max(fmaxf(fmaxf(v0, v1), fmaxf(v2, v3)));
    float es = (valid && sub == 0)
             ? (__expf(v0 - m) + __expf(v1 - m) + __expf(v2 - m) + __expf(v3 - m)) : 0.f;
    float ssum = wred_sum(es);
    float lse = m + logf(ssum);
    if (sub == 0 && valid) {
        float4 o = {v0 - lse, v1 - lse, v2 - lse, v3 - lse};
        *(float4*)(out + (size_t)n * 40 + 4 * l16) = o;
    }
}

extern "C" void kernel_launch(void* const* d_in, const int* in_sizes, int n_in,
                              void* d_out, int out_size, void* d_ws, size_t ws_size,
                              hipStream_t stream) {
    const float* x    = (const float*)d_in[0];
    const int*   ei   = (const int*)d_in[1];
    const float* W1   = (const float*)d_in[2];
    const float* a1s  = (const float*)d_in[3];
    const float* a1d  = (const float*)d_in[4];
    const float* b1   = (const float*)d_in[5];
    const float* g1   = (const float*)d_in[6];
    const float* be1  = (const float*)d_in[7];
    const float* mn1  = (const float*)d_in[8];
    const float* vr1  = (const float*)d_in[9];
    const float* W2   = (const float*)d_in[10];
    const float* a2s  = (const float*)d_in[11];
    const float* a2d  = (const float*)d_in[12];
    const float* b2   = (const float*)d_in[13];
    float* out = (float*)d_out;

    const int N  = in_sizes[0] / 128;
    const int E  = in_sizes[1] / 2;
    const int Et = E + N;
    const int nScanB  = (N + SCAN_CHUNK - 1) / SCAN_CHUNK;
    const int nCoarse = (N + COARSE_NPB - 1) >> COARSE_SHIFT;
    const int chunk   = (Et + NBLK - 1) / NBLK;

    char* p = (char*)d_ws;
    auto alloc = [&](size_t bytes) -> void* {
        void* r = (void*)p;
        p += (bytes + 255) & ~(size_t)255;
        return r;
    };
    int*      deg    = (int*)alloc((size_t)N * 4);
    int*      offs   = (int*)alloc((size_t)(N + 1) * 4);
    int*      bsum   = (int*)alloc((size_t)(nScanB + 1) * 4);
    int*      bpre   = (int*)alloc((size_t)(nScanB + 1) * 4);
    int*      hist   = (int*)alloc((size_t)nCoarse * NBLK * 4);
    unsigned* staged = (unsigned*)alloc((size_t)Et * 4);
    int*      csr    = (int*)alloc((size_t)Et * 4);
    unsigned* h1b    = (unsigned*)alloc((size_t)N * 64 * 4);
    float*    al1sv  = (float*)alloc((size_t)N * 2 * 4);
    float*    al1dv  = (float*)alloc((size_t)N * 2 * 4);
    float*    hbn    = (float*)alloc((size_t)N * 128 * 4);
    unsigned* h2b    = (unsigned*)alloc((size_t)N * 32 * 4);
    float*    al2sv  = (float*)alloc((size_t)N * 4);
    float*    al2dv  = (float*)alloc((size_t)N * 4);
    (void)ws_size;

    hipMemsetAsync(deg, 0, (size_t)N * 4, stream);

    hist_fused<<<NBLK, 256, 0, stream>>>(ei, E, Et, chunk, deg, hist, nCoarse);
    scan_blocksum<<<nScanB, 256, 0, stream>>>(deg, bsum, N);
    scan_bsums<<<1, 1024, 0, stream>>>(bsum, bpre, nScanB);
    scan_scatter<<<nScanB, 256, 0, stream>>>(deg, bpre, offs, N, nScanB);
    part_scan<<<nCoarse, 64, 0, stream>>>(hist, offs, nCoarse);
    part_scatter<<<NBLK, 256, 0, stream>>>(ei, E, Et, chunk, hist, staged, nCoarse);
    fine_place<<<nCoarse, 1024, 0, stream>>>(staged, offs, csr, N, nCoarse);

    gemm1_tiled<<<(N + 63) / 64, 256, 0, stream>>>(x, W1, a1s, a1d, h1b, al1sv, al1dv, N);
    softagg1_kernel<<<(N + 3) / 4, 256, 0, stream>>>(offs, csr, h1b, al1sv, al1dv,
                                                     b1, g1, be1, mn1, vr1, hbn, N);

    gemm2_tiled<<<(N + 63) / 64, 256, 0, stream>>>(hbn, W2, a2s, a2d, h2b, al2sv, al2dv, N);
    softagg2_kernel<<<(N + 3) / 4, 256, 0, stream>>>(offs, csr, h2b, al2sv, al2dv, b2, out, N);
}

// Round 8
// 277.171 us; speedup vs baseline: 1.9204x; 1.1510x over previous
//
#include <hip/hip_runtime.h>
#include <hip/hip_bf16.h>

#define NEG_SLOPE 0.2f
#define BN_EPS 1e-5f

// two-level counting sort for CSR build (coarse bucket = 512 nodes; needs nCoarse <= 128)
#define NBLK 256
#define COARSE_SHIFT 9
#define COARSE_NPB 512

__device__ __forceinline__ float wred_sum(float v) {
    #pragma unroll
    for (int m = 32; m > 0; m >>= 1) v += __shfl_xor(v, m);
    return v;
}
__device__ __forceinline__ float wred_max(float v) {
    #pragma unroll
    for (int m = 32; m > 0; m >>= 1) v = fmaxf(v, __shfl_xor(v, m));
    return v;
}

__device__ __forceinline__ unsigned pack_bf16(float a, float b) {
    __hip_bfloat162 t;
    t.x = __float2bfloat16(a);
    t.y = __float2bfloat16(b);
    return *(unsigned*)&t;
}
__device__ __forceinline__ float2 unpack_bf16(unsigned u) {
    __hip_bfloat162 t = *(__hip_bfloat162*)&u;
    return {__bfloat162float(t.x), __bfloat162float(t.y)};
}

// order-preserving float<->uint encoding (for atomicMax on floats; 0 encodes below all reals)
__device__ __forceinline__ unsigned enc_ord(float f) {
    unsigned u = __float_as_uint(f);
    return (u & 0x80000000u) ? ~u : (u | 0x80000000u);
}
__device__ __forceinline__ float dec_ord(unsigned e) {
    unsigned u = (e & 0x80000000u) ? (e ^ 0x80000000u) : ~e;
    return __uint_as_float(u);
}

// ---- stage 1a: per-block coarse histogram (LDS only, no global atomics) ----
__global__ __launch_bounds__(256) void part_hist(const int* __restrict__ ei, int E, int Et,
                                                 int chunk, int* __restrict__ hist, int nCoarse) {
    __shared__ int h[128];
    int b = blockIdx.x, t = threadIdx.x;
    if (t < 128) h[t] = 0;
    __syncthreads();
    int beg = b * chunk, end = min(beg + chunk, Et);
    for (int idx = beg + t; idx < end; idx += 256) {
        int d = (idx < E) ? ei[E + idx] : (idx - E);
        atomicAdd(&h[d >> COARSE_SHIFT], 1);
    }
    __syncthreads();
    if (t < nCoarse) hist[t * NBLK + b] = h[t];
}

// ---- per-coarse-bucket totals ----
__global__ __launch_bounds__(256) void coarse_total(const int* __restrict__ hist,
                                                    int* __restrict__ ctot) {
    __shared__ int red[256];
    int c = blockIdx.x, t = threadIdx.x;
    red[t] = hist[c * NBLK + t];
    __syncthreads();
    for (int off = 128; off > 0; off >>= 1) {
        if (t < off) red[t] += red[t + off];
        __syncthreads();
    }
    if (t == 0) ctot[c] = red[0];
}

// ---- exclusive scan of <=128 coarse totals -> cbase ----
__global__ __launch_bounds__(128) void coarse_scan(const int* __restrict__ ctot,
                                                   int* __restrict__ cbase, int nCoarse) {
    __shared__ int s[128];
    int t = threadIdx.x;
    int v = (t < nCoarse) ? ctot[t] : 0;
    s[t] = v;
    __syncthreads();
    for (int off = 1; off < 128; off <<= 1) {
        int u = (t >= off) ? s[t - off] : 0;
        __syncthreads();
        s[t] += u;
        __syncthreads();
    }
    if (t < nCoarse) cbase[t] = s[t] - v;
    if (t == 127) cbase[nCoarse] = s[127];
}

// ---- per-(bucket,block) base offsets: scan NBLK block counts within each bucket ----
__global__ __launch_bounds__(64) void part_scan(int* __restrict__ hist,
                                                const int* __restrict__ cbase, int nCoarse) {
    int c = blockIdx.x, t = threadIdx.x;
    int base = cbase[c];
    int idx = c * NBLK + 4 * t;
    int4 v = *(int4*)&hist[idx];
    int sl = v.x + v.y + v.z + v.w;
    int inc = sl;
    #pragma unroll
    for (int off = 1; off < 64; off <<= 1) {
        int u = __shfl_up(inc, off);
        if (t >= off) inc += u;
    }
    int exc = inc - sl + base;
    int4 o;
    o.x = exc;
    o.y = exc + v.x;
    o.z = exc + v.x + v.y;
    o.w = exc + v.x + v.y + v.z;
    *(int4*)&hist[idx] = o;
}

// ---- scatter into coarse-sorted staging (LDS cursors, private slices) ----
__global__ __launch_bounds__(256) void part_scatter(const int* __restrict__ ei, int E, int Et,
                                                    int chunk, const int* __restrict__ hist,
                                                    unsigned* __restrict__ staged, int nCoarse) {
    __shared__ int cur[128];
    int b = blockIdx.x, t = threadIdx.x;
    if (t < nCoarse) cur[t] = hist[t * NBLK + b];
    __syncthreads();
    int beg = b * chunk, end = min(beg + chunk, Et);
    for (int idx = beg + t; idx < end; idx += 256) {
        int s, d;
        if (idx < E) { s = ei[idx]; d = ei[E + idx]; }
        else         { s = idx - E; d = idx - E; }
        int c = d >> COARSE_SHIFT;
        int pos = atomicAdd(&cur[c], 1);
        staged[pos] = ((unsigned)s << COARSE_SHIFT) | (unsigned)(d & (COARSE_NPB - 1));
    }
}

// ---- fine placement + per-node offs derivation (512-bin LDS hist + in-block scan) ----
__global__ __launch_bounds__(512) void fine_place(const unsigned* __restrict__ staged,
                                                  const int* __restrict__ cbase,
                                                  int* __restrict__ offs,
                                                  int* __restrict__ csr, int Nn, int nCoarse) {
    __shared__ int hcnt[COARSE_NPB];
    __shared__ int scn[COARSE_NPB];
    int b = blockIdx.x, t = threadIdx.x;
    int node0 = b << COARSE_SHIFT;
    int nloc = min(COARSE_NPB, Nn - node0);
    hcnt[t] = 0;
    __syncthreads();
    int ebeg = cbase[b], eend = cbase[b + 1];
    for (int p = ebeg + t; p < eend; p += 512) {
        atomicAdd(&hcnt[staged[p] & (COARSE_NPB - 1)], 1);
    }
    __syncthreads();
    int val = hcnt[t];
    scn[t] = val;
    __syncthreads();
    for (int off = 1; off < COARSE_NPB; off <<= 1) {
        int u = (t >= off) ? scn[t - off] : 0;
        __syncthreads();
        scn[t] += u;
        __syncthreads();
    }
    int exc = ebeg + scn[t] - val;
    if (t < nloc) offs[node0 + t] = exc;
    if (b == nCoarse - 1 && t == 0) offs[Nn] = eend;
    hcnt[t] = exc;          // reuse as cursor
    __syncthreads();
    for (int p = ebeg + t; p < eend; p += 512) {
        unsigned v = staged[p];
        int pos = atomicAdd(&hcnt[v & (COARSE_NPB - 1)], 1);
        csr[pos] = (int)(v >> COARSE_SHIFT);
    }
}

// ---------------- Layer 1 GEMM + fused al1 + global al-max, bf16-packed output ----------------
__global__ __launch_bounds__(256) void gemm1_tiled(const float* __restrict__ x,
                                                   const float* __restrict__ W,
                                                   const float* __restrict__ a1s,
                                                   const float* __restrict__ a1d,
                                                   unsigned* __restrict__ h1b,
                                                   float* __restrict__ als,
                                                   float* __restrict__ ald,
                                                   unsigned* __restrict__ gmax, int Nn) {
    __shared__ float As[64][33];
    __shared__ float Bs[32][132];
    __shared__ float4 red4[64][17];
    int t  = threadIdx.x;
    int tx = t & 15;
    int ty = t >> 4;
    int br = blockIdx.x * 64;

    float acc[4][8];
    #pragma unroll
    for (int i = 0; i < 4; ++i)
        #pragma unroll
        for (int j = 0; j < 8; ++j) acc[i][j] = 0.f;

    int k4  = t & 7;
    int rowA = t >> 3;

    for (int k0 = 0; k0 < 128; k0 += 32) {
        #pragma unroll
        for (int i = 0; i < 2; ++i) {
            int r  = rowA + 32 * i;
            int gr = min(br + r, Nn - 1);
            float4 v = *(const float4*)(x + (size_t)gr * 128 + k0 + 4 * k4);
            As[r][4 * k4 + 0] = v.x; As[r][4 * k4 + 1] = v.y;
            As[r][4 * k4 + 2] = v.z; As[r][4 * k4 + 3] = v.w;
        }
        #pragma unroll
        for (int i = 0; i < 4; ++i) {
            int f  = t + 256 * i;
            int kk = f >> 5, c4 = f & 31;
            *(float4*)&Bs[kk][4 * c4] = *(const float4*)(W + (size_t)(k0 + kk) * 128 + 4 * c4);
        }
        __syncthreads();
        #pragma unroll
        for (int kk = 0; kk < 32; ++kk) {
            float4 b0 = *(const float4*)&Bs[kk][4 * tx];
            float4 b1 = *(const float4*)&Bs[kk][64 + 4 * tx];
            #pragma unroll
            for (int i = 0; i < 4; ++i) {
                float a = As[4 * ty + i][kk];
                acc[i][0] += a * b0.x; acc[i][1] += a * b0.y;
                acc[i][2] += a * b0.z; acc[i][3] += a * b0.w;
                acc[i][4] += a * b1.x; acc[i][5] += a * b1.y;
                acc[i][6] += a * b1.z; acc[i][7] += a * b1.w;
            }
        }
        __syncthreads();
    }
    float s_lo[4], s_hi[4], d_lo[4], d_hi[4];
    #pragma unroll
    for (int j = 0; j < 4; ++j) {
        s_lo[j] = a1s[4 * tx + j];      s_hi[j] = a1s[64 + 4 * tx + j];
        d_lo[j] = a1d[4 * tx + j];      d_hi[j] = a1d[64 + 4 * tx + j];
    }
    #pragma unroll
    for (int i = 0; i < 4; ++i) {
        float4 pp = {0.f, 0.f, 0.f, 0.f};
        #pragma unroll
        for (int j = 0; j < 4; ++j) {
            pp.x += acc[i][j] * s_lo[j];
            pp.y += acc[i][4 + j] * s_hi[j];
            pp.z += acc[i][j] * d_lo[j];
            pp.w += acc[i][4 + j] * d_hi[j];
        }
        red4[4 * ty + i][tx] = pp;
        int r = br + 4 * ty + i;
        if (r < Nn) {
            uint2 lo = {pack_bf16(acc[i][0], acc[i][1]), pack_bf16(acc[i][2], acc[i][3])};
            uint2 hi = {pack_bf16(acc[i][4], acc[i][5]), pack_bf16(acc[i][6], acc[i][7])};
            *(uint2*)(h1b + (size_t)r * 64 + 2 * tx)      = lo;
            *(uint2*)(h1b + (size_t)r * 64 + 32 + 2 * tx) = hi;
        }
    }
    __syncthreads();
    if (t < 64) {
        int r = br + t;
        float4 s = {0.f, 0.f, 0.f, 0.f};
        #pragma unroll
        for (int xx = 0; xx < 16; ++xx) {
            float4 p = red4[t][xx];
            s.x += p.x; s.y += p.y; s.z += p.z; s.w += p.w;
        }
        if (r < Nn) {
            als[r * 2] = s.x; als[r * 2 + 1] = s.y;
            ald[r * 2] = s.z; ald[r * 2 + 1] = s.w;
        }
        // rows >= Nn hold clamped duplicates of row Nn-1 (safe for max)
        float m0 = wred_max(s.x);
        float m1 = wred_max(s.y);
        if (t == 0) {
            atomicMax(&gmax[0], enc_ord(m0));
            atomicMax(&gmax[1], enc_ord(m1));
        }
    }
}

// ---------------- single-pass fused softmax+agg, layer 1 (+ bias+BN+ReLU) ----------------
// uses global als-max bound: bound = leaky(M_h + ald[n]) >= all edge logits
__global__ __launch_bounds__(256) void softagg1_kernel(const int* __restrict__ offs, const int* __restrict__ csr,
                            const unsigned* __restrict__ h1b,
                            const float* __restrict__ als, const float* __restrict__ ald,
                            const unsigned* __restrict__ gmax,
                            const float* __restrict__ b1, const float* __restrict__ gam,
                            const float* __restrict__ bet, const float* __restrict__ mean,
                            const float* __restrict__ var, float* __restrict__ hbn, int Nn) {
    int wid = threadIdx.x >> 6, lane = threadIdx.x & 63;
    int n = blockIdx.x * 4 + wid;
    if (n >= Nn) return;
    int b = offs[n], e = offs[n + 1];
    int sub = lane >> 4;
    int l16 = lane & 15;
    int head = l16 >> 3;
    float aldh = ald[n * 2 + head];
    float bound = dec_ord(gmax[head]) + aldh;
    bound = (bound > 0.f) ? bound : NEG_SLOPE * bound;

    float acc[8];
    #pragma unroll
    for (int j = 0; j < 8; ++j) acc[j] = 0.f;
    float den = 0.f;
    for (int p = b + sub; p < e; p += 4) {
        int s = csr[p];
        float al = als[s * 2 + head] + aldh;
        al = (al > 0.f) ? al : NEG_SLOPE * al;
        float ev = __expf(al - bound);
        uint4 v = *(const uint4*)(h1b + (size_t)s * 64 + 4 * l16);
        float2 f0 = unpack_bf16(v.x), f1 = unpack_bf16(v.y);
        float2 f2 = unpack_bf16(v.z), f3 = unpack_bf16(v.w);
        acc[0] += f0.x * ev; acc[1] += f0.y * ev;
        acc[2] += f1.x * ev; acc[3] += f1.y * ev;
        acc[4] += f2.x * ev; acc[5] += f2.y * ev;
        acc[6] += f3.x * ev; acc[7] += f3.y * ev;
        den += ev;
    }
    #pragma unroll
    for (int j = 0; j < 8; ++j) {
        acc[j] += __shfl_xor(acc[j], 16);
        acc[j] += __shfl_xor(acc[j], 32);
    }
    den += __shfl_xor(den, 16);
    den += __shfl_xor(den, 32);
    if (sub == 0) {
        float inv = 1.f / (den + 1e-16f);
        int c = 8 * l16;
        #pragma unroll
        for (int half = 0; half < 2; ++half) {
            int cc = c + 4 * half;
            float4 bb = *(const float4*)(b1 + cc);
            float4 gg = *(const float4*)(gam + cc);
            float4 be = *(const float4*)(bet + cc);
            float4 mm = *(const float4*)(mean + cc);
            float4 vv = *(const float4*)(var + cc);
            float4 o;
            o.x = fmaxf((acc[4*half+0] * inv + bb.x - mm.x) * rsqrtf(vv.x + BN_EPS) * gg.x + be.x, 0.f);
            o.y = fmaxf((acc[4*half+1] * inv + bb.y - mm.y) * rsqrtf(vv.y + BN_EPS) * gg.y + be.y, 0.f);
            o.z = fmaxf((acc[4*half+2] * inv + bb.z - mm.z) * rsqrtf(vv.z + BN_EPS) * gg.z + be.z, 0.f);
            o.w = fmaxf((acc[4*half+3] * inv + bb.w - mm.w) * rsqrtf(vv.w + BN_EPS) * gg.w + be.w, 0.f);
            *(float4*)(hbn + (size_t)n * 128 + cc) = o;
        }
    }
}

// ---------------- layer 2 GEMM tiled + fused al2 + global al-max, bf16-packed output ----------------
__global__ __launch_bounds__(256) void gemm2_tiled(const float* __restrict__ hbn,
                                                   const float* __restrict__ W2,
                                                   const float* __restrict__ a2s,
                                                   const float* __restrict__ a2d,
                                                   unsigned* __restrict__ h2b,
                                                   float* __restrict__ als, float* __restrict__ ald,
                                                   unsigned* __restrict__ gmax, int Nn) {
    __shared__ float As[64][33];
    __shared__ float Bs[128][68];
    __shared__ float redS[64][17];
    __shared__ float redD[64][17];
    int t  = threadIdx.x;
    int tx = t & 15;
    int ty = t >> 4;
    int br = blockIdx.x * 64;

    #pragma unroll
    for (int i = 0; i < 8; ++i) {
        int f  = t + 256 * i;
        int kk = f >> 4, c4 = f & 15;
        float4 v = {0.f, 0.f, 0.f, 0.f};
        if (c4 < 10) v = *(const float4*)(W2 + (size_t)kk * 40 + 4 * c4);
        *(float4*)&Bs[kk][4 * c4] = v;
    }
    float as4[4], ad4[4];
    #pragma unroll
    for (int j = 0; j < 4; ++j) {
        int c = 4 * tx + j;
        as4[j] = (c < 40) ? a2s[c] : 0.f;
        ad4[j] = (c < 40) ? a2d[c] : 0.f;
    }

    float acc[4][4];
    #pragma unroll
    for (int i = 0; i < 4; ++i)
        #pragma unroll
        for (int j = 0; j < 4; ++j) acc[i][j] = 0.f;

    int k4  = t & 7;
    int rowA = t >> 3;
    __syncthreads();

    for (int k0 = 0; k0 < 128; k0 += 32) {
        #pragma unroll
        for (int i = 0; i < 2; ++i) {
            int r  = rowA + 32 * i;
            int gr = min(br + r, Nn - 1);
            float4 v = *(const float4*)(hbn + (size_t)gr * 128 + k0 + 4 * k4);
            As[r][4 * k4 + 0] = v.x; As[r][4 * k4 + 1] = v.y;
            As[r][4 * k4 + 2] = v.z; As[r][4 * k4 + 3] = v.w;
        }
        __syncthreads();
        #pragma unroll
        for (int kk = 0; kk < 32; ++kk) {
            float4 b0 = *(const float4*)&Bs[k0 + kk][4 * tx];
            #pragma unroll
            for (int i = 0; i < 4; ++i) {
                float a = As[4 * ty + i][kk];
                acc[i][0] += a * b0.x; acc[i][1] += a * b0.y;
                acc[i][2] += a * b0.z; acc[i][3] += a * b0.w;
            }
        }
        __syncthreads();
    }
    #pragma unroll
    for (int i = 0; i < 4; ++i) {
        redS[4 * ty + i][tx] = acc[i][0] * as4[0] + acc[i][1] * as4[1] + acc[i][2] * as4[2] + acc[i][3] * as4[3];
        redD[4 * ty + i][tx] = acc[i][0] * ad4[0] + acc[i][1] * ad4[1] + acc[i][2] * ad4[2] + acc[i][3] * ad4[3];
        int r = br + 4 * ty + i;
        if (r < Nn) {
            uint2 pk = {pack_bf16(acc[i][0], acc[i][1]), pack_bf16(acc[i][2], acc[i][3])};
            *(uint2*)(h2b + (size_t)r * 32 + 2 * tx) = pk;
        }
    }
    __syncthreads();
    if (t < 64) {
        int r = br + t;
        float sS = 0.f, sD = 0.f;
        #pragma unroll
        for (int xx = 0; xx < 16; ++xx) { sS += redS[t][xx]; sD += redD[t][xx]; }
        if (r < Nn) { als[r] = sS; ald[r] = sD; }
        float m = wred_max(sS);
        if (t == 0) atomicMax(&gmax[2], enc_ord(m));
    }
}

// ---------------- single-pass fused softmax+agg, layer 2 (+ bias + log_softmax) ----------------
__global__ __launch_bounds__(256) void softagg2_kernel(const int* __restrict__ offs, const int* __restrict__ csr,
                            const unsigned* __restrict__ h2b,
                            const float* __restrict__ als, const float* __restrict__ ald,
                            const unsigned* __restrict__ gmax,
                            const float* __restrict__ b2,
                            float* __restrict__ out, int Nn) {
    int wid = threadIdx.x >> 6, lane = threadIdx.x & 63;
    int n = blockIdx.x * 4 + wid;
    if (n >= Nn) return;
    int b = offs[n], e = offs[n + 1];
    float aldn = ald[n];
    float bound = dec_ord(gmax[2]) + aldn;
    bound = (bound > 0.f) ? bound : NEG_SLOPE * bound;

    int sub = lane >> 4;
    int l16 = lane & 15;
    float acc[4];
    #pragma unroll
    for (int j = 0; j < 4; ++j) acc[j] = 0.f;
    float den = 0.f;
    for (int p = b + sub; p < e; p += 4) {
        int s = csr[p];
        float l = als[s] + aldn;
        l = (l > 0.f) ? l : NEG_SLOPE * l;
        float ev = __expf(l - bound);
        uint2 v = *(const uint2*)(h2b + (size_t)s * 32 + 2 * l16);
        float2 f0 = unpack_bf16(v.x), f1 = unpack_bf16(v.y);
        acc[0] += f0.x * ev; acc[1] += f0.y * ev;
        acc[2] += f1.x * ev; acc[3] += f1.y * ev;
        den += ev;
    }
    #pragma unroll
    for (int j = 0; j < 4; ++j) {
        acc[j] += __shfl_xor(acc[j], 16);
        acc[j] += __shfl_xor(acc[j], 32);
    }
    den += __shfl_xor(den, 16);
    den += __shfl_xor(den, 32);
    float inv = 1.f / (den + 1e-16f);
    bool valid = (l16 < 10);
    float v0 = -1e30f, v1 = -1e30f, v2 = -1e30f, v3 = -1e30f;
    if (valid) {
        int c = 4 * l16;
        v0 = acc[0] * inv + b2[c];
        v1 = acc[1] * inv + b2[c + 1];
        v2 = acc[2] * inv + b2[c + 2];
        v3 = acc[3] * inv + b2[c + 3];
    }
    float m = wred_max(fmaxf(fmaxf(v0, v1), fmaxf(v2, v3)));
    float es = (valid && sub == 0)
             ? (__expf(v0 - m) + __expf(v1 - m) + __expf(v2 - m) + __expf(v3 - m)) : 0.f;
    float ssum = wred_sum(es);
    float lse = m + logf(ssum);
    if (sub == 0 && valid) {
        float4 o = {v0 - lse, v1 - lse, v2 - lse, v3 - lse};
        *(float4*)(out + (size_t)n * 40 + 4 * l16) = o;
    }
}

extern "C" void kernel_launch(void* const* d_in, const int* in_sizes, int n_in,
                              void* d_out, int out_size, void* d_ws, size_t ws_size,
                              hipStream_t stream) {
    const float* x    = (const float*)d_in[0];
    const int*   ei   = (const int*)d_in[1];
    const float* W1   = (const float*)d_in[2];
    const float* a1s  = (const float*)d_in[3];
    const float* a1d  = (const float*)d_in[4];
    const float* b1   = (const float*)d_in[5];
    const float* g1   = (const float*)d_in[6];
    const float* be1  = (const float*)d_in[7];
    const float* mn1  = (const float*)d_in[8];
    const float* vr1  = (const float*)d_in[9];
    const float* W2   = (const float*)d_in[10];
    const float* a2s  = (const float*)d_in[11];
    const float* a2d  = (const float*)d_in[12];
    const float* b2   = (const float*)d_in[13];
    float* out = (float*)d_out;

    const int N  = in_sizes[0] / 128;
    const int E  = in_sizes[1] / 2;
    const int Et = E + N;
    const int nCoarse = (N + COARSE_NPB - 1) >> COARSE_SHIFT;   // 98 for N=50000 (<=128)
    const int chunk   = (Et + NBLK - 1) / NBLK;

    char* p = (char*)d_ws;
    auto alloc = [&](size_t bytes) -> void* {
        void* r = (void*)p;
        p += (bytes + 255) & ~(size_t)255;
        return r;
    };
    int*      hist   = (int*)alloc((size_t)nCoarse * NBLK * 4);
    int*      ctot   = (int*)alloc((size_t)nCoarse * 4);
    int*      cbase  = (int*)alloc((size_t)(nCoarse + 1) * 4);
    int*      offs   = (int*)alloc((size_t)(N + 1) * 4);
    unsigned* staged = (unsigned*)alloc((size_t)Et * 4);
    int*      csr    = (int*)alloc((size_t)Et * 4);
    unsigned* h1b    = (unsigned*)alloc((size_t)N * 64 * 4);
    float*    al1sv  = (float*)alloc((size_t)N * 2 * 4);
    float*    al1dv  = (float*)alloc((size_t)N * 2 * 4);
    float*    hbn    = (float*)alloc((size_t)N * 128 * 4);
    unsigned* h2b    = (unsigned*)alloc((size_t)N * 32 * 4);
    float*    al2sv  = (float*)alloc((size_t)N * 4);
    float*    al2dv  = (float*)alloc((size_t)N * 4);
    unsigned* gmax   = (unsigned*)alloc(4 * 4);
    (void)ws_size;

    hipMemsetAsync(gmax, 0, 16, stream);   // encoded 0 < all real floats

    // CSR build (no global atomics anywhere)
    part_hist<<<NBLK, 256, 0, stream>>>(ei, E, Et, chunk, hist, nCoarse);
    coarse_total<<<nCoarse, 256, 0, stream>>>(hist, ctot);
    coarse_scan<<<1, 128, 0, stream>>>(ctot, cbase, nCoarse);
    part_scan<<<nCoarse, 64, 0, stream>>>(hist, cbase, nCoarse);
    part_scatter<<<NBLK, 256, 0, stream>>>(ei, E, Et, chunk, hist, staged, nCoarse);
    fine_place<<<nCoarse, 512, 0, stream>>>(staged, cbase, offs, csr, N, nCoarse);

    gemm1_tiled<<<(N + 63) / 64, 256, 0, stream>>>(x, W1, a1s, a1d, h1b, al1sv, al1dv, gmax, N);
    softagg1_kernel<<<(N + 3) / 4, 256, 0, stream>>>(offs, csr, h1b, al1sv, al1dv, gmax,
                                                     b1, g1, be1, mn1, vr1, hbn, N);

    gemm2_tiled<<<(N + 63) / 64, 256, 0, stream>>>(hbn, W2, a2s, a2d, h2b, al2sv, al2dv, gmax, N);
    softagg2_kernel<<<(N + 3) / 4, 256, 0, stream>>>(offs, csr, h2b, al2sv, al2dv, gmax, b2, out, N);
}

// Round 9
// 267.616 us; speedup vs baseline: 1.9890x; 1.0357x over previous
//
#include <hip/hip_runtime.h>
#include <hip/hip_bf16.h>

#define NEG_SLOPE 0.2f
#define BN_EPS 1e-5f

// two-level counting sort for CSR build (coarse bucket = 512 nodes; needs nCoarse <= 128)
#define NBLK 256
#define COARSE_SHIFT 9
#define COARSE_NPB 512

__device__ __forceinline__ float wred_sum(float v) {
    #pragma unroll
    for (int m = 32; m > 0; m >>= 1) v += __shfl_xor(v, m);
    return v;
}
__device__ __forceinline__ float wred_max(float v) {
    #pragma unroll
    for (int m = 32; m > 0; m >>= 1) v = fmaxf(v, __shfl_xor(v, m));
    return v;
}
// sum across the 16 lanes sharing ty (xor over tx bits 0..3)
__device__ __forceinline__ float xor16_sum(float v) {
    #pragma unroll
    for (int m = 1; m < 16; m <<= 1) v += __shfl_xor(v, m);
    return v;
}

__device__ __forceinline__ unsigned pack_bf16(float a, float b) {
    __hip_bfloat162 t;
    t.x = __float2bfloat16(a);
    t.y = __float2bfloat16(b);
    return *(unsigned*)&t;
}
__device__ __forceinline__ float2 unpack_bf16(unsigned u) {
    __hip_bfloat162 t = *(__hip_bfloat162*)&u;
    return {__bfloat162float(t.x), __bfloat162float(t.y)};
}

// order-preserving float<->uint encoding (atomicMax on floats; 0 encodes below all reals)
__device__ __forceinline__ unsigned enc_ord(float f) {
    unsigned u = __float_as_uint(f);
    return (u & 0x80000000u) ? ~u : (u | 0x80000000u);
}
__device__ __forceinline__ float dec_ord(unsigned e) {
    unsigned u = (e & 0x80000000u) ? (e ^ 0x80000000u) : ~e;
    return __uint_as_float(u);
}

// ---- stage 1a: per-block coarse histogram (LDS only, no global atomics) ----
__global__ __launch_bounds__(256) void part_hist(const int* __restrict__ ei, int E, int Et,
                                                 int chunk, int* __restrict__ hist, int nCoarse) {
    __shared__ int h[128];
    int b = blockIdx.x, t = threadIdx.x;
    if (t < 128) h[t] = 0;
    __syncthreads();
    int beg = b * chunk, end = min(beg + chunk, Et);
    for (int idx = beg + t; idx < end; idx += 256) {
        int d = (idx < E) ? ei[E + idx] : (idx - E);
        atomicAdd(&h[d >> COARSE_SHIFT], 1);
    }
    __syncthreads();
    if (t < nCoarse) hist[t * NBLK + b] = h[t];
}

__global__ __launch_bounds__(256) void coarse_total(const int* __restrict__ hist,
                                                    int* __restrict__ ctot) {
    __shared__ int red[256];
    int c = blockIdx.x, t = threadIdx.x;
    red[t] = hist[c * NBLK + t];
    __syncthreads();
    for (int off = 128; off > 0; off >>= 1) {
        if (t < off) red[t] += red[t + off];
        __syncthreads();
    }
    if (t == 0) ctot[c] = red[0];
}

__global__ __launch_bounds__(128) void coarse_scan(const int* __restrict__ ctot,
                                                   int* __restrict__ cbase, int nCoarse) {
    __shared__ int s[128];
    int t = threadIdx.x;
    int v = (t < nCoarse) ? ctot[t] : 0;
    s[t] = v;
    __syncthreads();
    for (int off = 1; off < 128; off <<= 1) {
        int u = (t >= off) ? s[t - off] : 0;
        __syncthreads();
        s[t] += u;
        __syncthreads();
    }
    if (t < nCoarse) cbase[t] = s[t] - v;
    if (t == 127) cbase[nCoarse] = s[127];
}

__global__ __launch_bounds__(64) void part_scan(int* __restrict__ hist,
                                                const int* __restrict__ cbase, int nCoarse) {
    int c = blockIdx.x, t = threadIdx.x;
    int base = cbase[c];
    int idx = c * NBLK + 4 * t;
    int4 v = *(int4*)&hist[idx];
    int sl = v.x + v.y + v.z + v.w;
    int inc = sl;
    #pragma unroll
    for (int off = 1; off < 64; off <<= 1) {
        int u = __shfl_up(inc, off);
        if (t >= off) inc += u;
    }
    int exc = inc - sl + base;
    int4 o;
    o.x = exc;
    o.y = exc + v.x;
    o.z = exc + v.x + v.y;
    o.w = exc + v.x + v.y + v.z;
    *(int4*)&hist[idx] = o;
}

__global__ __launch_bounds__(256) void part_scatter(const int* __restrict__ ei, int E, int Et,
                                                    int chunk, const int* __restrict__ hist,
                                                    unsigned* __restrict__ staged, int nCoarse) {
    __shared__ int cur[128];
    int b = blockIdx.x, t = threadIdx.x;
    if (t < nCoarse) cur[t] = hist[t * NBLK + b];
    __syncthreads();
    int beg = b * chunk, end = min(beg + chunk, Et);
    for (int idx = beg + t; idx < end; idx += 256) {
        int s, d;
        if (idx < E) { s = ei[idx]; d = ei[E + idx]; }
        else         { s = idx - E; d = idx - E; }
        int c = d >> COARSE_SHIFT;
        int pos = atomicAdd(&cur[c], 1);
        staged[pos] = ((unsigned)s << COARSE_SHIFT) | (unsigned)(d & (COARSE_NPB - 1));
    }
}

__global__ __launch_bounds__(512) void fine_place(const unsigned* __restrict__ staged,
                                                  const int* __restrict__ cbase,
                                                  int* __restrict__ offs,
                                                  int* __restrict__ csr, int Nn, int nCoarse) {
    __shared__ int hcnt[COARSE_NPB];
    __shared__ int scn[COARSE_NPB];
    int b = blockIdx.x, t = threadIdx.x;
    int node0 = b << COARSE_SHIFT;
    int nloc = min(COARSE_NPB, Nn - node0);
    hcnt[t] = 0;
    __syncthreads();
    int ebeg = cbase[b], eend = cbase[b + 1];
    for (int p = ebeg + t; p < eend; p += 512) {
        atomicAdd(&hcnt[staged[p] & (COARSE_NPB - 1)], 1);
    }
    __syncthreads();
    int val = hcnt[t];
    scn[t] = val;
    __syncthreads();
    for (int off = 1; off < COARSE_NPB; off <<= 1) {
        int u = (t >= off) ? scn[t - off] : 0;
        __syncthreads();
        scn[t] += u;
        __syncthreads();
    }
    int exc = ebeg + scn[t] - val;
    if (t < nloc) offs[node0 + t] = exc;
    if (b == nCoarse - 1 && t == 0) offs[Nn] = eend;
    hcnt[t] = exc;
    __syncthreads();
    for (int p = ebeg + t; p < eend; p += 512) {
        unsigned v = staged[p];
        int pos = atomicAdd(&hcnt[v & (COARSE_NPB - 1)], 1);
        csr[pos] = (int)(v >> COARSE_SHIFT);
    }
}

// ---------------- Layer 1 GEMM (128x128 tile, 8x8 micro, transposed-A LDS) + fused al1 ----------------
__global__ __launch_bounds__(256) void gemm1_tiled(const float* __restrict__ x,
                                                   const float* __restrict__ W,
                                                   const float* __restrict__ a1s,
                                                   const float* __restrict__ a1d,
                                                   unsigned* __restrict__ h1b,
                                                   float* __restrict__ als,
                                                   float* __restrict__ ald, int Nn) {
    __shared__ float Ast[32][132];   // [k][row] transposed
    __shared__ float Bs[32][132];    // [k][col]
    int t  = threadIdx.x;
    int tx = t & 15;                 // cols 8tx..8tx+7
    int ty = t >> 4;                 // rows 8ty..8ty+7
    int br = blockIdx.x * 128;

    float acc[8][8];
    #pragma unroll
    for (int i = 0; i < 8; ++i)
        #pragma unroll
        for (int j = 0; j < 8; ++j) acc[i][j] = 0.f;

    int k4   = t & 7;                // k-group for A staging
    int rowA = t >> 3;               // 0..31

    for (int k0 = 0; k0 < 128; k0 += 32) {
        // stage A transposed: 128 rows x 32 k
        #pragma unroll
        for (int i = 0; i < 4; ++i) {
            int r  = rowA + 32 * i;
            int gr = min(br + r, Nn - 1);
            float4 v = *(const float4*)(x + (size_t)gr * 128 + k0 + 4 * k4);
            Ast[4 * k4 + 0][r] = v.x; Ast[4 * k4 + 1][r] = v.y;
            Ast[4 * k4 + 2][r] = v.z; Ast[4 * k4 + 3][r] = v.w;
        }
        // stage B: 32 k x 128 cols
        #pragma unroll
        for (int i = 0; i < 4; ++i) {
            int f  = t + 256 * i;
            int kk = f >> 5, c4 = f & 31;
            *(float4*)&Bs[kk][4 * c4] = *(const float4*)(W + (size_t)(k0 + kk) * 128 + 4 * c4);
        }
        __syncthreads();
        #pragma unroll 8
        for (int kk = 0; kk < 32; ++kk) {
            float4 a0 = *(const float4*)&Ast[kk][8 * ty];
            float4 a1 = *(const float4*)&Ast[kk][8 * ty + 4];
            float4 b0 = *(const float4*)&Bs[kk][8 * tx];
            float4 b1 = *(const float4*)&Bs[kk][8 * tx + 4];
            float av[8] = {a0.x, a0.y, a0.z, a0.w, a1.x, a1.y, a1.z, a1.w};
            float bv[8] = {b0.x, b0.y, b0.z, b0.w, b1.x, b1.y, b1.z, b1.w};
            #pragma unroll
            for (int i = 0; i < 8; ++i)
                #pragma unroll
                for (int j = 0; j < 8; ++j) acc[i][j] += av[i] * bv[j];
        }
        __syncthreads();
    }

    // attention coeff slices for this thread's 8 cols (global col = 8tx+j, a1s/a1d flat [128])
    float a_s[8], a_d[8];
    #pragma unroll
    for (int j = 0; j < 8; ++j) { a_s[j] = a1s[8 * tx + j]; a_d[j] = a1d[8 * tx + j]; }
    bool h0 = (tx < 8);

    #pragma unroll
    for (int i = 0; i < 8; ++i) {
        int r = br + 8 * ty + i;
        // h1b write: cols 8tx..8tx+7 -> uint4 at offset 4tx
        if (r < Nn) {
            uint4 pk;
            pk.x = pack_bf16(acc[i][0], acc[i][1]);
            pk.y = pack_bf16(acc[i][2], acc[i][3]);
            pk.z = pack_bf16(acc[i][4], acc[i][5]);
            pk.w = pack_bf16(acc[i][6], acc[i][7]);
            *(uint4*)(h1b + (size_t)r * 64 + 4 * tx) = pk;
        }
        // al partials (this thread's cols are entirely in one head)
        float ps = 0.f, pd = 0.f;
        #pragma unroll
        for (int j = 0; j < 8; ++j) { ps += acc[i][j] * a_s[j]; pd += acc[i][j] * a_d[j]; }
        float s0 = xor16_sum(h0 ? ps : 0.f);
        float s1 = xor16_sum(h0 ? 0.f : ps);
        float d0 = xor16_sum(h0 ? pd : 0.f);
        float d1 = xor16_sum(h0 ? 0.f : pd);
        if (tx == 0 && r < Nn) {
            als[r * 2] = s0; als[r * 2 + 1] = s1;
            ald[r * 2] = d0; ald[r * 2 + 1] = d1;
        }
    }
}

// ---- global max of als per head (few atomics, separate tiny kernel) ----
template <int H>
__global__ __launch_bounds__(256) void almax_kernel(const float* __restrict__ als,
                                                    unsigned* __restrict__ gmax,
                                                    int off, int Nn) {
    __shared__ float red[4][H];
    int t = threadIdx.x;
    float m[H];
    #pragma unroll
    for (int h = 0; h < H; ++h) m[h] = -1e30f;
    for (int n = blockIdx.x * 256 + t; n < Nn; n += gridDim.x * 256) {
        #pragma unroll
        for (int h = 0; h < H; ++h) m[h] = fmaxf(m[h], als[n * H + h]);
    }
    #pragma unroll
    for (int h = 0; h < H; ++h) m[h] = wred_max(m[h]);
    int wid = t >> 6;
    if ((t & 63) == 0) {
        #pragma unroll
        for (int h = 0; h < H; ++h) red[wid][h] = m[h];
    }
    __syncthreads();
    if (t == 0) {
        #pragma unroll
        for (int h = 0; h < H; ++h) {
            float mm = fmaxf(fmaxf(red[0][h], red[1][h]), fmaxf(red[2][h], red[3][h]));
            atomicMax(&gmax[off + h], enc_ord(mm));
        }
    }
}

// ---------------- single-pass fused softmax+agg, layer 1 (+ bias+BN+ReLU) ----------------
__global__ __launch_bounds__(256) void softagg1_kernel(const int* __restrict__ offs, const int* __restrict__ csr,
                            const unsigned* __restrict__ h1b,
                            const float* __restrict__ als, const float* __restrict__ ald,
                            const unsigned* __restrict__ gmax,
                            const float* __restrict__ b1, const float* __restrict__ gam,
                            const float* __restrict__ bet, const float* __restrict__ mean,
                            const float* __restrict__ var, float* __restrict__ hbn, int Nn) {
    int wid = threadIdx.x >> 6, lane = threadIdx.x & 63;
    int n = blockIdx.x * 4 + wid;
    if (n >= Nn) return;
    int b = offs[n], e = offs[n + 1];
    int sub = lane >> 4;
    int l16 = lane & 15;
    int head = l16 >> 3;
    float aldh = ald[n * 2 + head];
    float bound = dec_ord(gmax[head]) + aldh;
    bound = (bound > 0.f) ? bound : NEG_SLOPE * bound;

    float acc[8];
    #pragma unroll
    for (int j = 0; j < 8; ++j) acc[j] = 0.f;
    float den = 0.f;
    for (int p = b + sub; p < e; p += 4) {
        int s = csr[p];
        float al = als[s * 2 + head] + aldh;
        al = (al > 0.f) ? al : NEG_SLOPE * al;
        float ev = __expf(al - bound);
        uint4 v = *(const uint4*)(h1b + (size_t)s * 64 + 4 * l16);
        float2 f0 = unpack_bf16(v.x), f1 = unpack_bf16(v.y);
        float2 f2 = unpack_bf16(v.z), f3 = unpack_bf16(v.w);
        acc[0] += f0.x * ev; acc[1] += f0.y * ev;
        acc[2] += f1.x * ev; acc[3] += f1.y * ev;
        acc[4] += f2.x * ev; acc[5] += f2.y * ev;
        acc[6] += f3.x * ev; acc[7] += f3.y * ev;
        den += ev;
    }
    #pragma unroll
    for (int j = 0; j < 8; ++j) {
        acc[j] += __shfl_xor(acc[j], 16);
        acc[j] += __shfl_xor(acc[j], 32);
    }
    den += __shfl_xor(den, 16);
    den += __shfl_xor(den, 32);
    if (sub == 0) {
        float inv = 1.f / (den + 1e-16f);
        int c = 8 * l16;
        #pragma unroll
        for (int half = 0; half < 2; ++half) {
            int cc = c + 4 * half;
            float4 bb = *(const float4*)(b1 + cc);
            float4 gg = *(const float4*)(gam + cc);
            float4 be = *(const float4*)(bet + cc);
            float4 mm = *(const float4*)(mean + cc);
            float4 vv = *(const float4*)(var + cc);
            float4 o;
            o.x = fmaxf((acc[4*half+0] * inv + bb.x - mm.x) * rsqrtf(vv.x + BN_EPS) * gg.x + be.x, 0.f);
            o.y = fmaxf((acc[4*half+1] * inv + bb.y - mm.y) * rsqrtf(vv.y + BN_EPS) * gg.y + be.y, 0.f);
            o.z = fmaxf((acc[4*half+2] * inv + bb.z - mm.z) * rsqrtf(vv.z + BN_EPS) * gg.z + be.z, 0.f);
            o.w = fmaxf((acc[4*half+3] * inv + bb.w - mm.w) * rsqrtf(vv.w + BN_EPS) * gg.w + be.w, 0.f);
            *(float4*)(hbn + (size_t)n * 128 + cc) = o;
        }
    }
}

// ---------------- Layer 2 GEMM (128x64 tile, 8x4 micro, transposed-A LDS) + fused al2 ----------------
__global__ __launch_bounds__(256) void gemm2_tiled(const float* __restrict__ hbn,
                                                   const float* __restrict__ W2,
                                                   const float* __restrict__ a2s,
                                                   const float* __restrict__ a2d,
                                                   unsigned* __restrict__ h2b,
                                                   float* __restrict__ als, float* __restrict__ ald,
                                                   int Nn) {
    __shared__ float Ast[32][132];   // [k][row]
    __shared__ float Bs[32][68];     // [k][col] 64 cols padded (40..63 zero)
    int t  = threadIdx.x;
    int tx = t & 15;                 // cols 4tx..4tx+3
    int ty = t >> 4;                 // rows 8ty..8ty+7
    int br = blockIdx.x * 128;

    float as4[4], ad4[4];
    #pragma unroll
    for (int j = 0; j < 4; ++j) {
        int c = 4 * tx + j;
        as4[j] = (c < 40) ? a2s[c] : 0.f;
        ad4[j] = (c < 40) ? a2d[c] : 0.f;
    }

    float acc[8][4];
    #pragma unroll
    for (int i = 0; i < 8; ++i)
        #pragma unroll
        for (int j = 0; j < 4; ++j) acc[i][j] = 0.f;

    int k4   = t & 7;
    int rowA = t >> 3;

    for (int k0 = 0; k0 < 128; k0 += 32) {
        #pragma unroll
        for (int i = 0; i < 4; ++i) {
            int r  = rowA + 32 * i;
            int gr = min(br + r, Nn - 1);
            float4 v = *(const float4*)(hbn + (size_t)gr * 128 + k0 + 4 * k4);
            Ast[4 * k4 + 0][r] = v.x; Ast[4 * k4 + 1][r] = v.y;
            Ast[4 * k4 + 2][r] = v.z; Ast[4 * k4 + 3][r] = v.w;
        }
        // stage W2 chunk: 32 k x 64 cols (pad)
        #pragma unroll
        for (int i = 0; i < 2; ++i) {
            int f  = t + 256 * i;
            int kk = f >> 4, c4 = f & 15;
            float4 v = {0.f, 0.f, 0.f, 0.f};
            if (c4 < 10) v = *(const float4*)(W2 + (size_t)(k0 + kk) * 40 + 4 * c4);
            *(float4*)&Bs[kk][4 * c4] = v;
        }
        __syncthreads();
        #pragma unroll 8
        for (int kk = 0; kk < 32; ++kk) {
            float4 a0 = *(const float4*)&Ast[kk][8 * ty];
            float4 a1 = *(const float4*)&Ast[kk][8 * ty + 4];
            float4 b0 = *(const float4*)&Bs[kk][4 * tx];
            float av[8] = {a0.x, a0.y, a0.z, a0.w, a1.x, a1.y, a1.z, a1.w};
            #pragma unroll
            for (int i = 0; i < 8; ++i) {
                acc[i][0] += av[i] * b0.x; acc[i][1] += av[i] * b0.y;
                acc[i][2] += av[i] * b0.z; acc[i][3] += av[i] * b0.w;
            }
        }
        __syncthreads();
    }

    #pragma unroll
    for (int i = 0; i < 8; ++i) {
        int r = br + 8 * ty + i;
        if (r < Nn) {
            uint2 pk = {pack_bf16(acc[i][0], acc[i][1]), pack_bf16(acc[i][2], acc[i][3])};
            *(uint2*)(h2b + (size_t)r * 32 + 2 * tx) = pk;
        }
        float ps = acc[i][0] * as4[0] + acc[i][1] * as4[1] + acc[i][2] * as4[2] + acc[i][3] * as4[3];
        float pd = acc[i][0] * ad4[0] + acc[i][1] * ad4[1] + acc[i][2] * ad4[2] + acc[i][3] * ad4[3];
        float sS = xor16_sum(ps);
        float sD = xor16_sum(pd);
        if (tx == 0 && r < Nn) { als[r] = sS; ald[r] = sD; }
    }
}

// ---------------- single-pass fused softmax+agg, layer 2 (+ bias + log_softmax) ----------------
__global__ __launch_bounds__(256) void softagg2_kernel(const int* __restrict__ offs, const int* __restrict__ csr,
                            const unsigned* __restrict__ h2b,
                            const float* __restrict__ als, const float* __restrict__ ald,
                            const unsigned* __restrict__ gmax,
                            const float* __restrict__ b2,
                            float* __restrict__ out, int Nn) {
    int wid = threadIdx.x >> 6, lane = threadIdx.x & 63;
    int n = blockIdx.x * 4 + wid;
    if (n >= Nn) return;
    int b = offs[n], e = offs[n + 1];
    float aldn = ald[n];
    float bound = dec_ord(gmax[2]) + aldn;
    bound = (bound > 0.f) ? bound : NEG_SLOPE * bound;

    int sub = lane >> 4;
    int l16 = lane & 15;
    float acc[4];
    #pragma unroll
    for (int j = 0; j < 4; ++j) acc[j] = 0.f;
    float den = 0.f;
    for (int p = b + sub; p < e; p += 4) {
        int s = csr[p];
        float l = als[s] + aldn;
        l = (l > 0.f) ? l : NEG_SLOPE * l;
        float ev = __expf(l - bound);
        uint2 v = *(const uint2*)(h2b + (size_t)s * 32 + 2 * l16);
        float2 f0 = unpack_bf16(v.x), f1 = unpack_bf16(v.y);
        acc[0] += f0.x * ev; acc[1] += f0.y * ev;
        acc[2] += f1.x * ev; acc[3] += f1.y * ev;
        den += ev;
    }
    #pragma unroll
    for (int j = 0; j < 4; ++j) {
        acc[j] += __shfl_xor(acc[j], 16);
        acc[j] += __shfl_xor(acc[j], 32);
    }
    den += __shfl_xor(den, 16);
    den += __shfl_xor(den, 32);
    float inv = 1.f / (den + 1e-16f);
    bool valid = (l16 < 10);
    float v0 = -1e30f, v1 = -1e30f, v2 = -1e30f, v3 = -1e30f;
    if (valid) {
        int c = 4 * l16;
        v0 = acc[0] * inv + b2[c];
        v1 = acc[1] * inv + b2[c + 1];
        v2 = acc[2] * inv + b2[c + 2];
        v3 = acc[3] * inv + b2[c + 3];
    }
    float m = wred_max(fmaxf(fmaxf(v0, v1), fmaxf(v2, v3)));
    float es = (valid && sub == 0)
             ? (__expf(v0 - m) + __expf(v1 - m) + __expf(v2 - m) + __expf(v3 - m)) : 0.f;
    float ssum = wred_sum(es);
    float lse = m + logf(ssum);
    if (sub == 0 && valid) {
        float4 o = {v0 - lse, v1 - lse, v2 - lse, v3 - lse};
        *(float4*)(out + (size_t)n * 40 + 4 * l16) = o;
    }
}

extern "C" void kernel_launch(void* const* d_in, const int* in_sizes, int n_in,
                              void* d_out, int out_size, void* d_ws, size_t ws_size,
                              hipStream_t stream) {
    const float* x    = (const float*)d_in[0];
    const int*   ei   = (const int*)d_in[1];
    const float* W1   = (const float*)d_in[2];
    const float* a1s  = (const float*)d_in[3];
    const float* a1d  = (const float*)d_in[4];
    const float* b1   = (const float*)d_in[5];
    const float* g1   = (const float*)d_in[6];
    const float* be1  = (const float*)d_in[7];
    const float* mn1  = (const float*)d_in[8];
    const float* vr1  = (const float*)d_in[9];
    const float* W2   = (const float*)d_in[10];
    const float* a2s  = (const float*)d_in[11];
    const float* a2d  = (const float*)d_in[12];
    const float* b2   = (const float*)d_in[13];
    float* out = (float*)d_out;

    const int N  = in_sizes[0] / 128;
    const int E  = in_sizes[1] / 2;
    const int Et = E + N;
    const int nCoarse = (N + COARSE_NPB - 1) >> COARSE_SHIFT;
    const int chunk   = (Et + NBLK - 1) / NBLK;

    char* p = (char*)d_ws;
    auto alloc = [&](size_t bytes) -> void* {
        void* r = (void*)p;
        p += (bytes + 255) & ~(size_t)255;
        return r;
    };
    int*      hist   = (int*)alloc((size_t)nCoarse * NBLK * 4);
    int*      ctot   = (int*)alloc((size_t)nCoarse * 4);
    int*      cbase  = (int*)alloc((size_t)(nCoarse + 1) * 4);
    int*      offs   = (int*)alloc((size_t)(N + 1) * 4);
    unsigned* staged = (unsigned*)alloc((size_t)Et * 4);
    int*      csr    = (int*)alloc((size_t)Et * 4);
    unsigned* h1b    = (unsigned*)alloc((size_t)N * 64 * 4);
    float*    al1sv  = (float*)alloc((size_t)N * 2 * 4);
    float*    al1dv  = (float*)alloc((size_t)N * 2 * 4);
    float*    hbn    = (float*)alloc((size_t)N * 128 * 4);
    unsigned* h2b    = (unsigned*)alloc((size_t)N * 32 * 4);
    float*    al2sv  = (float*)alloc((size_t)N * 4);
    float*    al2dv  = (float*)alloc((size_t)N * 4);
    unsigned* gmax   = (unsigned*)alloc(4 * 4);
    (void)ws_size;

    hipMemsetAsync(gmax, 0, 16, stream);

    // CSR build (no global atomics anywhere)
    part_hist<<<NBLK, 256, 0, stream>>>(ei, E, Et, chunk, hist, nCoarse);
    coarse_total<<<nCoarse, 256, 0, stream>>>(hist, ctot);
    coarse_scan<<<1, 128, 0, stream>>>(ctot, cbase, nCoarse);
    part_scan<<<nCoarse, 64, 0, stream>>>(hist, cbase, nCoarse);
    part_scatter<<<NBLK, 256, 0, stream>>>(ei, E, Et, chunk, hist, staged, nCoarse);
    fine_place<<<nCoarse, 512, 0, stream>>>(staged, cbase, offs, csr, N, nCoarse);

    gemm1_tiled<<<(N + 127) / 128, 256, 0, stream>>>(x, W1, a1s, a1d, h1b, al1sv, al1dv, N);
    almax_kernel<2><<<64, 256, 0, stream>>>(al1sv, gmax, 0, N);
    softagg1_kernel<<<(N + 3) / 4, 256, 0, stream>>>(offs, csr, h1b, al1sv, al1dv, gmax,
                                                     b1, g1, be1, mn1, vr1, hbn, N);

    gemm2_tiled<<<(N + 127) / 128, 256, 0, stream>>>(hbn, W2, a2s, a2d, h2b, al2sv, al2dv, N);
    almax_kernel<1><<<64, 256, 0, stream>>>(al2sv, gmax, 2, N);
    softagg2_kernel<<<(N + 3) / 4, 256, 0, stream>>>(offs, csr, h2b, al2sv, al2dv, gmax, b2, out, N);
}

// Round 11
// 262.790 us; speedup vs baseline: 2.0255x; 1.0184x over previous
//
#include <hip/hip_runtime.h>
#include <hip/hip_bf16.h>

#define NEG_SLOPE 0.2f
#define BN_EPS 1e-5f

// two-level counting sort for CSR build (coarse bucket = 512 nodes; needs nCoarse <= 128)
#define NBLK 256
#define COARSE_SHIFT 9
#define COARSE_NPB 512

__device__ __forceinline__ float wred_sum(float v) {
    #pragma unroll
    for (int m = 32; m > 0; m >>= 1) v += __shfl_xor(v, m);
    return v;
}
__device__ __forceinline__ float wred_max(float v) {
    #pragma unroll
    for (int m = 32; m > 0; m >>= 1) v = fmaxf(v, __shfl_xor(v, m));
    return v;
}
__device__ __forceinline__ float xor16_sum(float v) {
    #pragma unroll
    for (int m = 1; m < 16; m <<= 1) v += __shfl_xor(v, m);
    return v;
}

__device__ __forceinline__ unsigned pack_bf16(float a, float b) {
    __hip_bfloat162 t;
    t.x = __float2bfloat16(a);
    t.y = __float2bfloat16(b);
    return *(unsigned*)&t;
}
__device__ __forceinline__ float2 unpack_bf16(unsigned u) {
    __hip_bfloat162 t = *(__hip_bfloat162*)&u;
    return {__bfloat162float(t.x), __bfloat162float(t.y)};
}

__device__ __forceinline__ unsigned enc_ord(float f) {
    unsigned u = __float_as_uint(f);
    return (u & 0x80000000u) ? ~u : (u | 0x80000000u);
}
__device__ __forceinline__ float dec_ord(unsigned e) {
    unsigned u = (e & 0x80000000u) ? (e ^ 0x80000000u) : ~e;
    return __uint_as_float(u);
}

// ---- CSR build: per-block coarse histogram (LDS only) ----
__global__ __launch_bounds__(256) void part_hist(const int* __restrict__ ei, int E, int Et,
                                                 int chunk, int* __restrict__ hist, int nCoarse) {
    __shared__ int h[128];
    int b = blockIdx.x, t = threadIdx.x;
    if (t < 128) h[t] = 0;
    __syncthreads();
    int beg = b * chunk, end = min(beg + chunk, Et);
    for (int idx = beg + t; idx < end; idx += 256) {
        int d = (idx < E) ? ei[E + idx] : (idx - E);
        atomicAdd(&h[d >> COARSE_SHIFT], 1);
    }
    __syncthreads();
    if (t < nCoarse) hist[t * NBLK + b] = h[t];
}

__global__ __launch_bounds__(256) void coarse_total(const int* __restrict__ hist,
                                                    int* __restrict__ ctot) {
    __shared__ int red[256];
    int c = blockIdx.x, t = threadIdx.x;
    red[t] = hist[c * NBLK + t];
    __syncthreads();
    for (int off = 128; off > 0; off >>= 1) {
        if (t < off) red[t] += red[t + off];
        __syncthreads();
    }
    if (t == 0) ctot[c] = red[0];
}

__global__ __launch_bounds__(128) void coarse_scan(const int* __restrict__ ctot,
                                                   int* __restrict__ cbase, int nCoarse) {
    __shared__ int s[128];
    int t = threadIdx.x;
    int v = (t < nCoarse) ? ctot[t] : 0;
    s[t] = v;
    __syncthreads();
    for (int off = 1; off < 128; off <<= 1) {
        int u = (t >= off) ? s[t - off] : 0;
        __syncthreads();
        s[t] += u;
        __syncthreads();
    }
    if (t < nCoarse) cbase[t] = s[t] - v;
    if (t == 127) cbase[nCoarse] = s[127];
}

__global__ __launch_bounds__(64) void part_scan(int* __restrict__ hist,
                                                const int* __restrict__ cbase, int nCoarse) {
    int c = blockIdx.x, t = threadIdx.x;
    int base = cbase[c];
    int idx = c * NBLK + 4 * t;
    int4 v = *(int4*)&hist[idx];
    int sl = v.x + v.y + v.z + v.w;
    int inc = sl;
    #pragma unroll
    for (int off = 1; off < 64; off <<= 1) {
        int u = __shfl_up(inc, off);
        if (t >= off) inc += u;
    }
    int exc = inc - sl + base;
    int4 o;
    o.x = exc;
    o.y = exc + v.x;
    o.z = exc + v.x + v.y;
    o.w = exc + v.x + v.y + v.z;
    *(int4*)&hist[idx] = o;
}

__global__ __launch_bounds__(256) void part_scatter(const int* __restrict__ ei, int E, int Et,
                                                    int chunk, const int* __restrict__ hist,
                                                    unsigned* __restrict__ staged, int nCoarse) {
    __shared__ int cur[128];
    int b = blockIdx.x, t = threadIdx.x;
    if (t < nCoarse) cur[t] = hist[t * NBLK + b];
    __syncthreads();
    int beg = b * chunk, end = min(beg + chunk, Et);
    for (int idx = beg + t; idx < end; idx += 256) {
        int s, d;
        if (idx < E) { s = ei[idx]; d = ei[E + idx]; }
        else         { s = idx - E; d = idx - E; }
        int c = d >> COARSE_SHIFT;
        int pos = atomicAdd(&cur[c], 1);
        staged[pos] = ((unsigned)s << COARSE_SHIFT) | (unsigned)(d & (COARSE_NPB - 1));
    }
}

__global__ __launch_bounds__(512) void fine_place(const unsigned* __restrict__ staged,
                                                  const int* __restrict__ cbase,
                                                  int* __restrict__ offs,
                                                  int* __restrict__ csr, int Nn, int nCoarse) {
    __shared__ int hcnt[COARSE_NPB];
    __shared__ int scn[COARSE_NPB];
    int b = blockIdx.x, t = threadIdx.x;
    int node0 = b << COARSE_SHIFT;
    int nloc = min(COARSE_NPB, Nn - node0);
    hcnt[t] = 0;
    __syncthreads();
    int ebeg = cbase[b], eend = cbase[b + 1];
    for (int p = ebeg + t; p < eend; p += 512) {
        atomicAdd(&hcnt[staged[p] & (COARSE_NPB - 1)], 1);
    }
    __syncthreads();
    int val = hcnt[t];
    scn[t] = val;
    __syncthreads();
    for (int off = 1; off < COARSE_NPB; off <<= 1) {
        int u = (t >= off) ? scn[t - off] : 0;
        __syncthreads();
        scn[t] += u;
        __syncthreads();
    }
    int exc = ebeg + scn[t] - val;
    if (t < nloc) offs[node0 + t] = exc;
    if (b == nCoarse - 1 && t == 0) offs[Nn] = eend;
    hcnt[t] = exc;
    __syncthreads();
    for (int p = ebeg + t; p < eend; p += 512) {
        unsigned v = staged[p];
        int pos = atomicAdd(&hcnt[v & (COARSE_NPB - 1)], 1);
        csr[pos] = (int)(v >> COARSE_SHIFT);
    }
}

// ---------------- Layer 1 GEMM (128x128 tile, 8x8 micro, transposed-A LDS) + fused al1 ----------------
__global__ __launch_bounds__(256) void gemm1_tiled(const float* __restrict__ x,
                                                   const float* __restrict__ W,
                                                   const float* __restrict__ a1s,
                                                   const float* __restrict__ a1d,
                                                   unsigned* __restrict__ h1b,
                                                   float* __restrict__ als,
                                                   float* __restrict__ ald, int Nn) {
    __shared__ float Ast[32][132];
    __shared__ float Bs[32][132];
    int t  = threadIdx.x;
    int tx = t & 15;
    int ty = t >> 4;
    int br = blockIdx.x * 128;

    float acc[8][8];
    #pragma unroll
    for (int i = 0; i < 8; ++i)
        #pragma unroll
        for (int j = 0; j < 8; ++j) acc[i][j] = 0.f;

    int k4   = t & 7;
    int rowA = t >> 3;

    for (int k0 = 0; k0 < 128; k0 += 32) {
        #pragma unroll
        for (int i = 0; i < 4; ++i) {
            int r  = rowA + 32 * i;
            int gr = min(br + r, Nn - 1);
            float4 v = *(const float4*)(x + (size_t)gr * 128 + k0 + 4 * k4);
            Ast[4 * k4 + 0][r] = v.x; Ast[4 * k4 + 1][r] = v.y;
            Ast[4 * k4 + 2][r] = v.z; Ast[4 * k4 + 3][r] = v.w;
        }
        #pragma unroll
        for (int i = 0; i < 4; ++i) {
            int f  = t + 256 * i;
            int kk = f >> 5, c4 = f & 31;
            *(float4*)&Bs[kk][4 * c4] = *(const float4*)(W + (size_t)(k0 + kk) * 128 + 4 * c4);
        }
        __syncthreads();
        #pragma unroll 8
        for (int kk = 0; kk < 32; ++kk) {
            float4 a0 = *(const float4*)&Ast[kk][8 * ty];
            float4 a1 = *(const float4*)&Ast[kk][8 * ty + 4];
            float4 b0 = *(const float4*)&Bs[kk][8 * tx];
            float4 b1 = *(const float4*)&Bs[kk][8 * tx + 4];
            float av[8] = {a0.x, a0.y, a0.z, a0.w, a1.x, a1.y, a1.z, a1.w};
            float bv[8] = {b0.x, b0.y, b0.z, b0.w, b1.x, b1.y, b1.z, b1.w};
            #pragma unroll
            for (int i = 0; i < 8; ++i)
                #pragma unroll
                for (int j = 0; j < 8; ++j) acc[i][j] += av[i] * bv[j];
        }
        __syncthreads();
    }

    float a_s[8], a_d[8];
    #pragma unroll
    for (int j = 0; j < 8; ++j) { a_s[j] = a1s[8 * tx + j]; a_d[j] = a1d[8 * tx + j]; }
    bool h0 = (tx < 8);

    #pragma unroll
    for (int i = 0; i < 8; ++i) {
        int r = br + 8 * ty + i;
        if (r < Nn) {
            uint4 pk;
            pk.x = pack_bf16(acc[i][0], acc[i][1]);
            pk.y = pack_bf16(acc[i][2], acc[i][3]);
            pk.z = pack_bf16(acc[i][4], acc[i][5]);
            pk.w = pack_bf16(acc[i][6], acc[i][7]);
            *(uint4*)(h1b + (size_t)r * 64 + 4 * tx) = pk;
        }
        float ps = 0.f, pd = 0.f;
        #pragma unroll
        for (int j = 0; j < 8; ++j) { ps += acc[i][j] * a_s[j]; pd += acc[i][j] * a_d[j]; }
        float s0 = xor16_sum(h0 ? ps : 0.f);
        float s1 = xor16_sum(h0 ? 0.f : ps);
        float d0 = xor16_sum(h0 ? pd : 0.f);
        float d1 = xor16_sum(h0 ? 0.f : pd);
        if (tx == 0 && r < Nn) {
            als[r * 2] = s0; als[r * 2 + 1] = s1;
            ald[r * 2] = d0; ald[r * 2 + 1] = d1;
        }
    }
}

// ---- global max of als per head + (block 0) BN scale/shift precompute ----
template <int H>
__global__ __launch_bounds__(256) void almax_kernel(const float* __restrict__ als,
                                                    unsigned* __restrict__ gmax, int off, int Nn,
                                                    const float* __restrict__ b1,
                                                    const float* __restrict__ g1,
                                                    const float* __restrict__ be1,
                                                    const float* __restrict__ mn1,
                                                    const float* __restrict__ vr1,
                                                    float* __restrict__ bnscale,
                                                    float* __restrict__ bnshift) {
    __shared__ float red[4][H];
    int t = threadIdx.x;
    if (bnscale && blockIdx.x == 0 && t < 128) {
        float sc = rsqrtf(vr1[t] + BN_EPS) * g1[t];
        bnscale[t] = sc;
        bnshift[t] = be1[t] + (b1[t] - mn1[t]) * sc;
    }
    float m[H];
    #pragma unroll
    for (int h = 0; h < H; ++h) m[h] = -1e30f;
    for (int n = blockIdx.x * 256 + t; n < Nn; n += gridDim.x * 256) {
        #pragma unroll
        for (int h = 0; h < H; ++h) m[h] = fmaxf(m[h], als[n * H + h]);
    }
    #pragma unroll
    for (int h = 0; h < H; ++h) m[h] = wred_max(m[h]);
    int wid = t >> 6;
    if ((t & 63) == 0) {
        #pragma unroll
        for (int h = 0; h < H; ++h) red[wid][h] = m[h];
    }
    __syncthreads();
    if (t == 0) {
        #pragma unroll
        for (int h = 0; h < H; ++h) {
            float mm = fmaxf(fmaxf(red[0][h], red[1][h]), fmaxf(red[2][h], red[3][h]));
            atomicMax(&gmax[off + h], enc_ord(mm));
        }
    }
}

// ---------------- two-phase fused softmax+agg, layer 1 (LDS handoff; folded BN+ReLU, fp32 out) ----------------
__global__ __launch_bounds__(256) void softagg1_kernel(const int* __restrict__ offs, const int* __restrict__ csr,
                            const unsigned* __restrict__ h1b,
                            const float* __restrict__ als, const float* __restrict__ ald,
                            const unsigned* __restrict__ gmax,
                            const float* __restrict__ bnscale, const float* __restrict__ bnshift,
                            float* __restrict__ hbn, int Nn) {
    __shared__ int   sh_s[4][64];
    __shared__ float sh_e0[4][64];
    __shared__ float sh_e1[4][64];
    int wid = threadIdx.x >> 6, lane = threadIdx.x & 63;
    int n = blockIdx.x * 4 + wid;
    if (n >= Nn) return;
    int b = offs[n], e = offs[n + 1];
    float2 aldn = *(const float2*)(ald + n * 2);
    float bd0 = dec_ord(gmax[0]) + aldn.x; bd0 = (bd0 > 0.f) ? bd0 : NEG_SLOPE * bd0;
    float bd1 = dec_ord(gmax[1]) + aldn.y; bd1 = (bd1 > 0.f) ? bd1 : NEG_SLOPE * bd1;

    int eslot = lane >> 3;   // 0..7 edge slots
    int l8    = lane & 7;    // col chunk: head0 cols 8l8.., head1 cols 64+8l8..
    float acc[16];
    #pragma unroll
    for (int j = 0; j < 16; ++j) acc[j] = 0.f;
    float den0 = 0.f, den1 = 0.f;

    for (int base = b; base < e; base += 64) {
        int cnt = min(64, e - base);
        // phase 1: one lane per edge — coalesced csr read, single als gather, one exp per edge
        int   s1 = 0;
        float e0r = 0.f, e1r = 0.f;
        if (lane < cnt) {
            s1 = csr[base + lane];
            float2 as = *(const float2*)(als + (size_t)s1 * 2);
            float l0 = as.x + aldn.x; l0 = (l0 > 0.f) ? l0 : NEG_SLOPE * l0;
            float l1 = as.y + aldn.y; l1 = (l1 > 0.f) ? l1 : NEG_SLOPE * l1;
            e0r = __expf(l0 - bd0);
            e1r = __expf(l1 - bd1);
            den0 += e0r; den1 += e1r;
        }
        sh_s[wid][lane]  = s1;
        sh_e0[wid][lane] = e0r;
        sh_e1[wid][lane] = e1r;
        // phase 2: 8 edges in flight; each edge's full 256B row read by its 8 lanes
        for (int i = eslot; i < cnt; i += 8) {
            int   s  = sh_s[wid][i];
            float e0 = sh_e0[wid][i];
            float e1 = sh_e1[wid][i];
            uint4 va = *(const uint4*)(h1b + (size_t)s * 64 + 4 * l8);
            uint4 vb = *(const uint4*)(h1b + (size_t)s * 64 + 32 + 4 * l8);
            float2 f;
            f = unpack_bf16(va.x); acc[0]  += f.x * e0; acc[1]  += f.y * e0;
            f = unpack_bf16(va.y); acc[2]  += f.x * e0; acc[3]  += f.y * e0;
            f = unpack_bf16(va.z); acc[4]  += f.x * e0; acc[5]  += f.y * e0;
            f = unpack_bf16(va.w); acc[6]  += f.x * e0; acc[7]  += f.y * e0;
            f = unpack_bf16(vb.x); acc[8]  += f.x * e1; acc[9]  += f.y * e1;
            f = unpack_bf16(vb.y); acc[10] += f.x * e1; acc[11] += f.y * e1;
            f = unpack_bf16(vb.z); acc[12] += f.x * e1; acc[13] += f.y * e1;
            f = unpack_bf16(vb.w); acc[14] += f.x * e1; acc[15] += f.y * e1;
        }
    }
    #pragma unroll
    for (int j = 0; j < 16; ++j) {
        acc[j] += __shfl_xor(acc[j], 8);
        acc[j] += __shfl_xor(acc[j], 16);
        acc[j] += __shfl_xor(acc[j], 32);
    }
    den0 = wred_sum(den0);
    den1 = wred_sum(den1);
    if (eslot == 0) {
        float inv0 = 1.f / (den0 + 1e-16f);
        float inv1 = 1.f / (den1 + 1e-16f);
        int c0 = 8 * l8, c1 = 64 + 8 * l8;
        float4 sa = *(const float4*)(bnscale + c0), sb = *(const float4*)(bnscale + c0 + 4);
        float4 ha = *(const float4*)(bnshift + c0), hb = *(const float4*)(bnshift + c0 + 4);
        float4 oa, ob;
        oa.x = fmaxf(acc[0] * inv0 * sa.x + ha.x, 0.f);
        oa.y = fmaxf(acc[1] * inv0 * sa.y + ha.y, 0.f);
        oa.z = fmaxf(acc[2] * inv0 * sa.z + ha.z, 0.f);
        oa.w = fmaxf(acc[3] * inv0 * sa.w + ha.w, 0.f);
        ob.x = fmaxf(acc[4] * inv0 * sb.x + hb.x, 0.f);
        ob.y = fmaxf(acc[5] * inv0 * sb.y + hb.y, 0.f);
        ob.z = fmaxf(acc[6] * inv0 * sb.z + hb.z, 0.f);
        ob.w = fmaxf(acc[7] * inv0 * sb.w + hb.w, 0.f);
        *(float4*)(hbn + (size_t)n * 128 + c0)     = oa;
        *(float4*)(hbn + (size_t)n * 128 + c0 + 4) = ob;
        float4 sc = *(const float4*)(bnscale + c1), sd = *(const float4*)(bnscale + c1 + 4);
        float4 hc = *(const float4*)(bnshift + c1), hd = *(const float4*)(bnshift + c1 + 4);
        float4 oc, od;
        oc.x = fmaxf(acc[8]  * inv1 * sc.x + hc.x, 0.f);
        oc.y = fmaxf(acc[9]  * inv1 * sc.y + hc.y, 0.f);
        oc.z = fmaxf(acc[10] * inv1 * sc.z + hc.z, 0.f);
        oc.w = fmaxf(acc[11] * inv1 * sc.w + hc.w, 0.f);
        od.x = fmaxf(acc[12] * inv1 * sd.x + hd.x, 0.f);
        od.y = fmaxf(acc[13] * inv1 * sd.y + hd.y, 0.f);
        od.z = fmaxf(acc[14] * inv1 * sd.z + hd.z, 0.f);
        od.w = fmaxf(acc[15] * inv1 * sd.w + hd.w, 0.f);
        *(float4*)(hbn + (size_t)n * 128 + c1)     = oc;
        *(float4*)(hbn + (size_t)n * 128 + c1 + 4) = od;
    }
}

// ---------------- Layer 2 GEMM (128x64 tile, 8x4 micro, transposed-A LDS, fp32 hbn) + fused al2 ----------------
__global__ __launch_bounds__(256) void gemm2_tiled(const float* __restrict__ hbn,
                                                   const float* __restrict__ W2,
                                                   const float* __restrict__ a2s,
                                                   const float* __restrict__ a2d,
                                                   unsigned* __restrict__ h2b,
                                                   float* __restrict__ als, float* __restrict__ ald,
                                                   int Nn) {
    __shared__ float Ast[32][132];
    __shared__ float Bs[32][68];
    int t  = threadIdx.x;
    int tx = t & 15;
    int ty = t >> 4;
    int br = blockIdx.x * 128;

    float as4[4], ad4[4];
    #pragma unroll
    for (int j = 0; j < 4; ++j) {
        int c = 4 * tx + j;
        as4[j] = (c < 40) ? a2s[c] : 0.f;
        ad4[j] = (c < 40) ? a2d[c] : 0.f;
    }

    float acc[8][4];
    #pragma unroll
    for (int i = 0; i < 8; ++i)
        #pragma unroll
        for (int j = 0; j < 4; ++j) acc[i][j] = 0.f;

    int k4   = t & 7;
    int rowA = t >> 3;

    for (int k0 = 0; k0 < 128; k0 += 32) {
        #pragma unroll
        for (int i = 0; i < 4; ++i) {
            int r  = rowA + 32 * i;
            int gr = min(br + r, Nn - 1);
            float4 v = *(const float4*)(hbn + (size_t)gr * 128 + k0 + 4 * k4);
            Ast[4 * k4 + 0][r] = v.x; Ast[4 * k4 + 1][r] = v.y;
            Ast[4 * k4 + 2][r] = v.z; Ast[4 * k4 + 3][r] = v.w;
        }
        #pragma unroll
        for (int i = 0; i < 2; ++i) {
            int f  = t + 256 * i;
            int kk = f >> 4, c4 = f & 15;
            float4 v = {0.f, 0.f, 0.f, 0.f};
            if (c4 < 10) v = *(const float4*)(W2 + (size_t)(k0 + kk) * 40 + 4 * c4);
            *(float4*)&Bs[kk][4 * c4] = v;
        }
        __syncthreads();
        #pragma unroll 8
        for (int kk = 0; kk < 32; ++kk) {
            float4 a0 = *(const float4*)&Ast[kk][8 * ty];
            float4 a1 = *(const float4*)&Ast[kk][8 * ty + 4];
            float4 b0 = *(const float4*)&Bs[kk][4 * tx];
            float av[8] = {a0.x, a0.y, a0.z, a0.w, a1.x, a1.y, a1.z, a1.w};
            #pragma unroll
            for (int i = 0; i < 8; ++i) {
                acc[i][0] += av[i] * b0.x; acc[i][1] += av[i] * b0.y;
                acc[i][2] += av[i] * b0.z; acc[i][3] += av[i] * b0.w;
            }
        }
        __syncthreads();
    }

    #pragma unroll
    for (int i = 0; i < 8; ++i) {
        int r = br + 8 * ty + i;
        if (r < Nn) {
            uint2 pk = {pack_bf16(acc[i][0], acc[i][1]), pack_bf16(acc[i][2], acc[i][3])};
            *(uint2*)(h2b + (size_t)r * 32 + 2 * tx) = pk;
        }
        float ps = acc[i][0] * as4[0] + acc[i][1] * as4[1] + acc[i][2] * as4[2] + acc[i][3] * as4[3];
        float pd = acc[i][0] * ad4[0] + acc[i][1] * ad4[1] + acc[i][2] * ad4[2] + acc[i][3] * ad4[3];
        float sS = xor16_sum(ps);
        float sD = xor16_sum(pd);
        if (tx == 0 && r < Nn) { als[r] = sS; ald[r] = sD; }
    }
}

// ---------------- two-phase fused softmax+agg, layer 2 (LDS handoff; + bias + log_softmax) ----------------
__global__ __launch_bounds__(256) void softagg2_kernel(const int* __restrict__ offs, const int* __restrict__ csr,
                            const unsigned* __restrict__ h2b,
                            const float* __restrict__ als, const float* __restrict__ ald,
                            const unsigned* __restrict__ gmax,
                            const float* __restrict__ b2,
                            float* __restrict__ out, int Nn) {
    __shared__ int   sh_s[4][64];
    __shared__ float sh_ev[4][64];
    int wid = threadIdx.x >> 6, lane = threadIdx.x & 63;
    int n = blockIdx.x * 4 + wid;
    if (n >= Nn) return;
    int b = offs[n], e = offs[n + 1];
    float aldn = ald[n];
    float bound = dec_ord(gmax[2]) + aldn;
    bound = (bound > 0.f) ? bound : NEG_SLOPE * bound;

    int eslot = lane >> 3;
    int l8    = lane & 7;    // cols 8l8..8l8+7 (valid l8<5)
    float acc[8];
    #pragma unroll
    for (int j = 0; j < 8; ++j) acc[j] = 0.f;
    float den = 0.f;

    for (int base = b; base < e; base += 64) {
        int cnt = min(64, e - base);
        int   s1 = 0;
        float evr = 0.f;
        if (lane < cnt) {
            s1 = csr[base + lane];
            float l = als[s1] + aldn;
            l = (l > 0.f) ? l : NEG_SLOPE * l;
            evr = __expf(l - bound);
            den += evr;
        }
        sh_s[wid][lane]  = s1;
        sh_ev[wid][lane] = evr;
        for (int i = eslot; i < cnt; i += 8) {
            int   s  = sh_s[wid][i];
            float ev = sh_ev[wid][i];
            uint4 v = *(const uint4*)(h2b + (size_t)s * 32 + 4 * l8);
            float2 f;
            f = unpack_bf16(v.x); acc[0] += f.x * ev; acc[1] += f.y * ev;
            f = unpack_bf16(v.y); acc[2] += f.x * ev; acc[3] += f.y * ev;
            f = unpack_bf16(v.z); acc[4] += f.x * ev; acc[5] += f.y * ev;
            f = unpack_bf16(v.w); acc[6] += f.x * ev; acc[7] += f.y * ev;
        }
    }
    #pragma unroll
    for (int j = 0; j < 8; ++j) {
        acc[j] += __shfl_xor(acc[j], 8);
        acc[j] += __shfl_xor(acc[j], 16);
        acc[j] += __shfl_xor(acc[j], 32);
    }
    den = wred_sum(den);
    float inv = 1.f / (den + 1e-16f);
    bool valid = (eslot == 0) && (l8 < 5);
    float vv[8];
    float lmax = -1e30f;
    if (valid) {
        int c = 8 * l8;
        #pragma unroll
        for (int j = 0; j < 8; ++j) {
            vv[j] = acc[j] * inv + b2[c + j];
            lmax = fmaxf(lmax, vv[j]);
        }
    }
    float m = wred_max(lmax);
    float es = 0.f;
    if (valid) {
        #pragma unroll
        for (int j = 0; j < 8; ++j) es += __expf(vv[j] - m);
    }
    float ssum = wred_sum(es);
    float lse = m + logf(ssum);
    if (valid) {
        float4 oa = {vv[0] - lse, vv[1] - lse, vv[2] - lse, vv[3] - lse};
        float4 ob = {vv[4] - lse, vv[5] - lse, vv[6] - lse, vv[7] - lse};
        *(float4*)(out + (size_t)n * 40 + 8 * l8)     = oa;
        *(float4*)(out + (size_t)n * 40 + 8 * l8 + 4) = ob;
    }
}

extern "C" void kernel_launch(void* const* d_in, const int* in_sizes, int n_in,
                              void* d_out, int out_size, void* d_ws, size_t ws_size,
                              hipStream_t stream) {
    const float* x    = (const float*)d_in[0];
    const int*   ei   = (const int*)d_in[1];
    const float* W1   = (const float*)d_in[2];
    const float* a1s  = (const float*)d_in[3];
    const float* a1d  = (const float*)d_in[4];
    const float* b1   = (const float*)d_in[5];
    const float* g1   = (const float*)d_in[6];
    const float* be1  = (const float*)d_in[7];
    const float* mn1  = (const float*)d_in[8];
    const float* vr1  = (const float*)d_in[9];
    const float* W2   = (const float*)d_in[10];
    const float* a2s  = (const float*)d_in[11];
    const float* a2d  = (const float*)d_in[12];
    const float* b2   = (const float*)d_in[13];
    float* out = (float*)d_out;

    const int N  = in_sizes[0] / 128;
    const int E  = in_sizes[1] / 2;
    const int Et = E + N;
    const int nCoarse = (N + COARSE_NPB - 1) >> COARSE_SHIFT;
    const int chunk   = (Et + NBLK - 1) / NBLK;

    char* p = (char*)d_ws;
    auto alloc = [&](size_t bytes) -> void* {
        void* r = (void*)p;
        p += (bytes + 255) & ~(size_t)255;
        return r;
    };
    int*      hist   = (int*)alloc((size_t)nCoarse * NBLK * 4);
    int*      ctot   = (int*)alloc((size_t)nCoarse * 4);
    int*      cbase  = (int*)alloc((size_t)(nCoarse + 1) * 4);
    int*      offs   = (int*)alloc((size_t)(N + 1) * 4);
    unsigned* staged = (unsigned*)alloc((size_t)Et * 4);
    int*      csr    = (int*)alloc((size_t)Et * 4);
    unsigned* h1b    = (unsigned*)alloc((size_t)N * 64 * 4);
    float*    al1sv  = (float*)alloc((size_t)N * 2 * 4);
    float*    al1dv  = (float*)alloc((size_t)N * 2 * 4);
    float*    hbn    = (float*)alloc((size_t)N * 128 * 4);
    unsigned* h2b    = (unsigned*)alloc((size_t)N * 32 * 4);
    float*    al2sv  = (float*)alloc((size_t)N * 4);
    float*    al2dv  = (float*)alloc((size_t)N * 4);
    unsigned* gmax   = (unsigned*)alloc(4 * 4);
    float*    bnscale= (float*)alloc(128 * 4);
    float*    bnshift= (float*)alloc(128 * 4);
    (void)ws_size;

    hipMemsetAsync(gmax, 0, 16, stream);

    part_hist<<<NBLK, 256, 0, stream>>>(ei, E, Et, chunk, hist, nCoarse);
    coarse_total<<<nCoarse, 256, 0, stream>>>(hist, ctot);
    coarse_scan<<<1, 128, 0, stream>>>(ctot, cbase, nCoarse);
    part_scan<<<nCoarse, 64, 0, stream>>>(hist, cbase, nCoarse);
    part_scatter<<<NBLK, 256, 0, stream>>>(ei, E, Et, chunk, hist, staged, nCoarse);
    fine_place<<<nCoarse, 512, 0, stream>>>(staged, cbase, offs, csr, N, nCoarse);

    gemm1_tiled<<<(N + 127) / 128, 256, 0, stream>>>(x, W1, a1s, a1d, h1b, al1sv, al1dv, N);
    almax_kernel<2><<<64, 256, 0, stream>>>(al1sv, gmax, 0, N, b1, g1, be1, mn1, vr1, bnscale, bnshift);
    softagg1_kernel<<<(N + 3) / 4, 256, 0, stream>>>(offs, csr, h1b, al1sv, al1dv, gmax,
                                                     bnscale, bnshift, hbn, N);

    gemm2_tiled<<<(N + 127) / 128, 256, 0, stream>>>(hbn, W2, a2s, a2d, h2b, al2sv, al2dv, N);
    almax_kernel<1><<<64, 256, 0, stream>>>(al2sv, gmax, 2, N, nullptr, nullptr, nullptr, nullptr,
                                            nullptr, nullptr, nullptr);
    softagg2_kernel<<<(N + 3) / 4, 256, 0, stream>>>(offs, csr, h2b, al2sv, al2dv, gmax, b2, out, N);
}